// Round 7
// baseline (1092.075 us; speedup 1.0000x reference)
//
#include <hip/hip_runtime.h>

#define H 128
#define SHIFT 9             // nodes per coarse bucket = 512
#define BN 512
#define MAXNB 256           // max coarse buckets (N <= 131072)
#define CHUNK 4096          // edges per scatter block
#define TILE 32             // nodes per fused agg+gemm block
#define TPAD 132            // LDS row stride (128+4): conflict-free phase-2 reads

// ============ graph build: two-level counting sort (no random 4B scatters) ============

__global__ __launch_bounds__(256) void hist_coarse_k(const int* __restrict__ dst,
                                                     int* __restrict__ coarse, int E, int NBv) {
    __shared__ int h[MAXNB];
    int tid = threadIdx.x;
    h[tid] = 0;
    if (tid + 256 < MAXNB) h[tid + 256] = 0;
    __syncthreads();
    for (int e = blockIdx.x * blockDim.x + tid; e < E; e += gridDim.x * blockDim.x)
        atomicAdd(&h[dst[e] >> SHIFT], 1);
    __syncthreads();
    if (tid < NBv && h[tid] > 0) atomicAdd(&coarse[tid], h[tid]);
    if (tid + 256 < NBv && h[tid + 256] > 0) atomicAdd(&coarse[tid + 256], h[tid + 256]);
}

__global__ void scan_coarse_k(const int* __restrict__ coarse, int* __restrict__ cbase,
                              int* __restrict__ gcur, int* __restrict__ offs,
                              int NBv, int N, int E) {
    if (blockIdx.x == 0 && threadIdx.x == 0) {
        int run = 0;
        for (int b = 0; b < NBv; ++b) { int v = coarse[b]; cbase[b] = run; gcur[b] = run; run += v; }
        cbase[NBv] = run;
        offs[N] = E;
    }
}

__global__ __launch_bounds__(256) void scatter_pairs_k(const int* __restrict__ src,
                                                       const int* __restrict__ dst,
                                                       int* __restrict__ gcur,
                                                       unsigned* __restrict__ pairbuf,
                                                       int E, int NBv) {
    __shared__ unsigned stage[CHUNK];
    __shared__ unsigned char stb[CHUNK];
    __shared__ int hist[MAXNB], basel[MAXNB], cur[MAXNB], gbase[MAXNB];
    __shared__ int total;
    int tid = threadIdx.x;
    int base = blockIdx.x * CHUNK;

    int mysrc[16], mydst[16];
    #pragma unroll
    for (int i = 0; i < 16; ++i) {
        int e = base + i * 256 + tid;
        if (e < E) { mysrc[i] = src[e]; mydst[i] = dst[e]; } else mydst[i] = -1;
    }
    hist[tid] = 0; hist[tid + 256] = 0;
    __syncthreads();
    #pragma unroll
    for (int i = 0; i < 16; ++i)
        if (mydst[i] >= 0) atomicAdd(&hist[mydst[i] >> SHIFT], 1);
    __syncthreads();
    if (tid == 0) {
        int run = 0;
        for (int b = 0; b < NBv; ++b) { basel[b] = run; run += hist[b]; }
        total = run;
    }
    __syncthreads();
    for (int b = tid; b < NBv; b += 256) {
        cur[b] = basel[b];
        if (hist[b] > 0) gbase[b] = atomicAdd(&gcur[b], hist[b]);
    }
    __syncthreads();
    #pragma unroll
    for (int i = 0; i < 16; ++i)
        if (mydst[i] >= 0) {
            int b = mydst[i] >> SHIFT;
            int slot = atomicAdd(&cur[b], 1);
            stage[slot] = ((unsigned)(mydst[i] & (BN - 1)) << 17) | (unsigned)mysrc[i];
            stb[slot] = (unsigned char)b;
        }
    __syncthreads();
    for (int s = tid; s < total; s += 256) {
        int b = stb[s];
        pairbuf[gbase[b] + (s - basel[b])] = stage[s];
    }
}

__global__ __launch_bounds__(512) void build_csr_k(const unsigned* __restrict__ pairbuf,
                                                   const int* __restrict__ cbase,
                                                   int* __restrict__ offs, float* __restrict__ dinv,
                                                   int* __restrict__ csr, int N) {
    __shared__ int hist[BN];
    __shared__ int cur[BN];
    __shared__ int ps[BN];
    int b = blockIdx.x, tid = threadIdx.x;
    int node0 = b << SHIFT;
    int e0 = cbase[b], e1 = cbase[b + 1];
    hist[tid] = 0;
    __syncthreads();
    for (int p = e0 + tid; p < e1; p += 512)
        atomicAdd(&hist[pairbuf[p] >> 17], 1);
    __syncthreads();
    int v0 = hist[tid];
    ps[tid] = v0;
    __syncthreads();
    for (int off = 1; off < BN; off <<= 1) {
        int t = (tid >= off) ? ps[tid - off] : 0;
        __syncthreads();
        ps[tid] += t;
        __syncthreads();
    }
    int g0 = e0 + ps[tid] - v0;
    int n0 = node0 + tid;
    if (n0 < N) { offs[n0] = g0; dinv[n0] = rsqrtf((float)(v0 + 1)); }
    cur[tid] = g0;
    __syncthreads();
    for (int p = e0 + tid; p < e1; p += 512) {
        unsigned v = pairbuf[p];
        int pos = atomicAdd(&cur[v >> 17], 1);
        csr[pos] = (int)(v & 0x1FFFFu);
    }
}

// ---------------- layer 1 (scalar input feature) ----------------

__global__ void s_k(const float* __restrict__ x, const float* __restrict__ dinv,
                    float* __restrict__ s, int n) {
    int i = blockIdx.x * blockDim.x + threadIdx.x;
    if (i < n) s[i] = x[i] * dinv[i];
}

// t_i = dinv_i*(s_i + sum s_src); emits packed (t, dinv) pairs
__global__ void agg1_k(const float* __restrict__ s, const int* __restrict__ offs,
                       const int* __restrict__ csr, const float* __restrict__ dinv,
                       float2* __restrict__ td, int n) {
    int i = blockIdx.x * blockDim.x + threadIdx.x;
    if (i >= n) return;
    float sum = s[i];
    int e0 = offs[i], e1 = offs[i + 1];
    float a0 = 0.f, a1 = 0.f, a2 = 0.f, a3 = 0.f;
    int p = e0;
    for (; p + 4 <= e1; p += 4) {
        a0 += s[csr[p]]; a1 += s[csr[p + 1]]; a2 += s[csr[p + 2]]; a3 += s[csr[p + 3]];
    }
    for (; p < e1; ++p) sum += s[csr[p]];
    sum += (a0 + a1) + (a2 + a3);
    float d = dinv[i];
    td[i] = make_float2(sum * d, d);
}

// ======= layer 2 fully fused: per-wave scalar-aggregate -> LDS tile -> GEMM(W2) =======
// U2_i = dinv_i * sum_{j in N(i)+self} dinv_j * relu(t_j*w1 + b1)  (rank-1 algebra)
// Z2_i = dinv_i ⊙ relu(U2_i @ W2 + b2)

__global__ __launch_bounds__(256) void l2_fused_k(const float2* __restrict__ td,
                                                  const int* __restrict__ offs,
                                                  const int* __restrict__ csr,
                                                  const float* __restrict__ w1,
                                                  const float* __restrict__ b1,
                                                  const float* __restrict__ W2,
                                                  const float* __restrict__ b2,
                                                  const float* __restrict__ dinv,
                                                  float* __restrict__ Z2, int n) {
    __shared__ float T[TILE][TPAD];
    int wave = threadIdx.x >> 6;
    int lane = threadIdx.x & 63;
    int base = blockIdx.x * TILE;

    float wa = w1[lane], wb = w1[lane + 64];
    float ba = b1[lane], bb = b1[lane + 64];

    // phase 1: each wave produces 8 rows
    for (int i = 0; i < 8; ++i) {
        int node = base + wave * 8 + i;
        float sa = 0.f, sb = 0.f;
        if (node < n) {
            float2 self = td[node];
            sa = fmaxf(fmaf(self.x, wa, ba), 0.f) * self.y;
            sb = fmaxf(fmaf(self.x, wb, bb), 0.f) * self.y;
            int e0 = offs[node], e1 = offs[node + 1];
            int p = e0;
            for (; p + 8 <= e1; p += 8) {
                float2 v[8];
                #pragma unroll
                for (int u = 0; u < 8; ++u) v[u] = td[csr[p + u]];
                #pragma unroll
                for (int u = 0; u < 8; ++u) {
                    sa = fmaf(fmaxf(fmaf(v[u].x, wa, ba), 0.f), v[u].y, sa);
                    sb = fmaf(fmaxf(fmaf(v[u].x, wb, bb), 0.f), v[u].y, sb);
                }
            }
            for (; p < e1; ++p) {
                float2 v = td[csr[p]];
                sa = fmaf(fmaxf(fmaf(v.x, wa, ba), 0.f), v.y, sa);
                sb = fmaf(fmaxf(fmaf(v.x, wb, bb), 0.f), v.y, sb);
            }
            sa *= self.y; sb *= self.y;
        }
        T[wave * 8 + i][lane]      = sa;
        T[wave * 8 + i][lane + 64] = sb;
    }
    __syncthreads();

    // phase 2: Z2 tile = dinv * relu(T @ W2 + b2); W2 streamed from global (L2-hot)
    int r  = threadIdx.x >> 3;          // 0..31
    int cc = threadIdx.x & 7;
    int c0 = cc * 16;
    int row = base + r;

    float acc[16];
    #pragma unroll
    for (int j = 0; j < 16; ++j) acc[j] = 0.f;

    for (int k4 = 0; k4 < H / 4; ++k4) {
        float4 a = *(const float4*)&T[r][k4 * 4];
        #pragma unroll
        for (int kk = 0; kk < 4; ++kk) {
            const float* wrow = W2 + (size_t)(k4 * 4 + kk) * H + c0;
            float w[16];
            *(float4*)(w + 0)  = *(const float4*)(wrow + 0);
            *(float4*)(w + 4)  = *(const float4*)(wrow + 4);
            *(float4*)(w + 8)  = *(const float4*)(wrow + 8);
            *(float4*)(w + 12) = *(const float4*)(wrow + 12);
            float av = ((const float*)&a)[kk];
            #pragma unroll
            for (int j = 0; j < 16; ++j) acc[j] = fmaf(av, w[j], acc[j]);
        }
    }

    if (row < n) {
        float sc = dinv[row];
        float* orow = Z2 + (size_t)row * H + c0;
        #pragma unroll
        for (int j4 = 0; j4 < 4; ++j4) {
            float4 o;
            o.x = fmaxf(acc[j4 * 4 + 0] + b2[c0 + j4 * 4 + 0], 0.f) * sc;
            o.y = fmaxf(acc[j4 * 4 + 1] + b2[c0 + j4 * 4 + 1], 0.f) * sc;
            o.z = fmaxf(acc[j4 * 4 + 2] + b2[c0 + j4 * 4 + 2], 0.f) * sc;
            o.w = fmaxf(acc[j4 * 4 + 3] + b2[c0 + j4 * 4 + 3], 0.f) * sc;
            *(float4*)(orow + j4 * 4) = o;
        }
    }
}

// ------- whole-wave gather of one node's neighbor-row sum -------

__device__ __forceinline__ float4 gather_row_sum(const float4* __restrict__ hs4,
                                                 const int* __restrict__ csr,
                                                 int node, int e0, int e1, int half, int l) {
    float4 acc[8];
    #pragma unroll
    for (int u = 0; u < 8; ++u) acc[u] = make_float4(0.f, 0.f, 0.f, 0.f);
    if (half == 0) acc[0] = hs4[(size_t)node * 32 + l];   // self loop
    int q = e0;
    for (; q + 15 < e1; q += 16) {
        int idx[8];
        #pragma unroll
        for (int u = 0; u < 8; ++u) idx[u] = csr[q + 2 * u + half];
        #pragma unroll
        for (int u = 0; u < 8; ++u) {
            float4 v = hs4[(size_t)idx[u] * 32 + l];
            acc[u].x += v.x; acc[u].y += v.y; acc[u].z += v.z; acc[u].w += v.w;
        }
    }
    for (; q + 7 < e1; q += 8) {
        int idx[4];
        #pragma unroll
        for (int u = 0; u < 4; ++u) idx[u] = csr[q + 2 * u + half];
        #pragma unroll
        for (int u = 0; u < 4; ++u) {
            float4 v = hs4[(size_t)idx[u] * 32 + l];
            acc[u].x += v.x; acc[u].y += v.y; acc[u].z += v.z; acc[u].w += v.w;
        }
    }
    for (; q < e1; q += 2) {
        int off = q + half;
        if (off < e1) {
            float4 v = hs4[(size_t)csr[off] * 32 + l];
            acc[0].x += v.x; acc[0].y += v.y; acc[0].z += v.z; acc[0].w += v.w;
        }
    }
    float4 sum;
    sum.x = ((acc[0].x + acc[1].x) + (acc[2].x + acc[3].x)) + ((acc[4].x + acc[5].x) + (acc[6].x + acc[7].x));
    sum.y = ((acc[0].y + acc[1].y) + (acc[2].y + acc[3].y)) + ((acc[4].y + acc[5].y) + (acc[6].y + acc[7].y));
    sum.z = ((acc[0].z + acc[1].z) + (acc[2].z + acc[3].z)) + ((acc[4].z + acc[5].z) + (acc[6].z + acc[7].z));
    sum.w = ((acc[0].w + acc[1].w) + (acc[2].w + acc[3].w)) + ((acc[4].w + acc[5].w) + (acc[6].w + acc[7].w));
    sum.x += __shfl_xor(sum.x, 32);
    sum.y += __shfl_xor(sum.y, 32);
    sum.z += __shfl_xor(sum.z, 32);
    sum.w += __shfl_xor(sum.w, 32);
    return sum;
}

// ======= layer 3 fully fused: per-wave row-gather -> LDS tile -> GEMM(W3) =======
// U3_i = dinv_i*(Z2_i + sum Z2_src);  h3_i = relu(U3_i @ W3 + b3)

__global__ __launch_bounds__(256) void agg_gemm3_k(const float* __restrict__ Z,
                                                   const int* __restrict__ offs,
                                                   const int* __restrict__ csr,
                                                   const float* __restrict__ dinv,
                                                   const float* __restrict__ W3,
                                                   const float* __restrict__ b3,
                                                   float* __restrict__ h3, int n) {
    __shared__ float T[TILE][TPAD];
    int wave = threadIdx.x >> 6;
    int lane = threadIdx.x & 63;
    int half = lane >> 5;
    int l = lane & 31;
    int base = blockIdx.x * TILE;
    const float4* Z4 = (const float4*)Z;

    // phase 1: each wave gathers 8 nodes' rows into the tile
    for (int i = 0; i < 8; ++i) {
        int node = base + wave * 8 + i;
        if (node < n) {
            float4 sum = gather_row_sum(Z4, csr, node, offs[node], offs[node + 1], half, l);
            if (half == 0) {
                float d = dinv[node];
                *(float4*)&T[wave * 8 + i][l * 4] = make_float4(sum.x * d, sum.y * d, sum.z * d, sum.w * d);
            }
        } else if (half == 0) {
            *(float4*)&T[wave * 8 + i][l * 4] = make_float4(0.f, 0.f, 0.f, 0.f);
        }
    }
    __syncthreads();

    // phase 2: h3 tile = relu(T @ W3 + b3); W3 streamed from global (L2-hot)
    int r  = threadIdx.x >> 3;
    int cc = threadIdx.x & 7;
    int c0 = cc * 16;
    int row = base + r;

    float acc[16];
    #pragma unroll
    for (int j = 0; j < 16; ++j) acc[j] = 0.f;

    for (int k4 = 0; k4 < H / 4; ++k4) {
        float4 a = *(const float4*)&T[r][k4 * 4];
        #pragma unroll
        for (int kk = 0; kk < 4; ++kk) {
            const float* wrow = W3 + (size_t)(k4 * 4 + kk) * H + c0;
            float w[16];
            *(float4*)(w + 0)  = *(const float4*)(wrow + 0);
            *(float4*)(w + 4)  = *(const float4*)(wrow + 4);
            *(float4*)(w + 8)  = *(const float4*)(wrow + 8);
            *(float4*)(w + 12) = *(const float4*)(wrow + 12);
            float av = ((const float*)&a)[kk];
            #pragma unroll
            for (int j = 0; j < 16; ++j) acc[j] = fmaf(av, w[j], acc[j]);
        }
    }

    if (row < n) {
        float* orow = h3 + (size_t)row * H + c0;
        #pragma unroll
        for (int j4 = 0; j4 < 4; ++j4) {
            float4 o;
            o.x = fmaxf(acc[j4 * 4 + 0] + b3[c0 + j4 * 4 + 0], 0.f);
            o.y = fmaxf(acc[j4 * 4 + 1] + b3[c0 + j4 * 4 + 1], 0.f);
            o.z = fmaxf(acc[j4 * 4 + 2] + b3[c0 + j4 * 4 + 2], 0.f);
            o.w = fmaxf(acc[j4 * 4 + 3] + b3[c0 + j4 * 4 + 3], 0.f);
            *(float4*)(orow + j4 * 4) = o;
        }
    }
}

// ---------------- pooling (binary search over sorted batch ids; overwrite, no atomics) --------

__global__ __launch_bounds__(128) void pool_k(const float* __restrict__ h, const int* __restrict__ batch,
                                              float* __restrict__ P, int n, int G) {
    int g = blockIdx.x, f = threadIdx.x;
    int lo = 0, hi = n;
    while (lo < hi) { int m = (lo + hi) >> 1; if (batch[m] < g) lo = m + 1; else hi = m; }
    int s0 = lo;
    hi = n;
    while (lo < hi) { int m = (lo + hi) >> 1; if (batch[m] < g + 1) lo = m + 1; else hi = m; }
    int s1 = lo;
    float a0 = 0.f, a1 = 0.f, a2 = 0.f, a3 = 0.f;
    int i = s0;
    for (; i + 4 <= s1; i += 4) {
        a0 += h[(size_t)i * H + f];
        a1 += h[(size_t)(i + 1) * H + f];
        a2 += h[(size_t)(i + 2) * H + f];
        a3 += h[(size_t)(i + 3) * H + f];
    }
    for (; i < s1; ++i) a0 += h[(size_t)i * H + f];
    float sum = (a0 + a1) + (a2 + a3);
    float c = (float)(s1 - s0); if (c < 1.f) c = 1.f;
    P[(size_t)g * H + f] = sum / c;
}

// ------- fused MLP head: relu(@Wl1+bl1) + relu(@Wl2+bl2) + dot Wl3 + bl3 -------

__global__ __launch_bounds__(256) void head_k(const float* __restrict__ P,
                                              const float* __restrict__ Wl1, const float* __restrict__ bl1,
                                              const float* __restrict__ Wl2, const float* __restrict__ bl2,
                                              const float* __restrict__ Wl3, const float* __restrict__ bl3,
                                              float* __restrict__ out, int G) {
    __shared__ float Wb[H * H];
    __shared__ float Tl[H * 133];
    __shared__ float w3l[H];
    int tid = threadIdx.x;
    int g0 = blockIdx.x * 128;

    if (tid < 128) w3l[tid] = Wl3[tid];
    for (int i = tid; i < H * H / 4; i += 256) ((float4*)Wb)[i] = ((const float4*)Wl1)[i];
    __syncthreads();

    const int cc = tid & 7, rg = tid >> 3, c0 = cc * 16;
    float acc[4][16];

    #pragma unroll
    for (int r = 0; r < 4; ++r)
        #pragma unroll
        for (int j = 0; j < 16; ++j) acc[r][j] = 0.f;
    const float4* P4 = (const float4*)P;
    for (int k4 = 0; k4 < H / 4; ++k4) {
        float4 a[4];
        #pragma unroll
        for (int r = 0; r < 4; ++r) a[r] = P4[(size_t)(g0 + rg * 4 + r) * 32 + k4];
        const float* wbase = Wb + (k4 * 4) * H + c0;
        #pragma unroll
        for (int kk = 0; kk < 4; ++kk) {
            float w[16];
            *(float4*)(w + 0)  = *(const float4*)(wbase + kk * H + 0);
            *(float4*)(w + 4)  = *(const float4*)(wbase + kk * H + 4);
            *(float4*)(w + 8)  = *(const float4*)(wbase + kk * H + 8);
            *(float4*)(w + 12) = *(const float4*)(wbase + kk * H + 12);
            float av[4];
            #pragma unroll
            for (int r = 0; r < 4; ++r) av[r] = ((const float*)&a[r])[kk];
            #pragma unroll
            for (int r = 0; r < 4; ++r)
                #pragma unroll
                for (int j = 0; j < 16; ++j)
                    acc[r][j] = fmaf(av[r], w[j], acc[r][j]);
        }
    }
    #pragma unroll
    for (int r = 0; r < 4; ++r) {
        int rl = rg * 4 + r;
        #pragma unroll
        for (int j = 0; j < 16; ++j)
            Tl[rl * 133 + c0 + j] = fmaxf(acc[r][j] + bl1[c0 + j], 0.f);
    }
    __syncthreads();
    for (int i = tid; i < H * H / 4; i += 256) ((float4*)Wb)[i] = ((const float4*)Wl2)[i];
    __syncthreads();

    #pragma unroll
    for (int r = 0; r < 4; ++r)
        #pragma unroll
        for (int j = 0; j < 16; ++j) acc[r][j] = 0.f;
    for (int k4 = 0; k4 < H / 4; ++k4) {
        float4 a[4];
        #pragma unroll
        for (int r = 0; r < 4; ++r) a[r] = *(const float4*)(Tl + (rg * 4 + r) * 133 + k4 * 4);
        const float* wbase = Wb + (k4 * 4) * H + c0;
        #pragma unroll
        for (int kk = 0; kk < 4; ++kk) {
            float w[16];
            *(float4*)(w + 0)  = *(const float4*)(wbase + kk * H + 0);
            *(float4*)(w + 4)  = *(const float4*)(wbase + kk * H + 4);
            *(float4*)(w + 8)  = *(const float4*)(wbase + kk * H + 8);
            *(float4*)(w + 12) = *(const float4*)(wbase + kk * H + 12);
            float av[4];
            #pragma unroll
            for (int r = 0; r < 4; ++r) av[r] = ((const float*)&a[r])[kk];
            #pragma unroll
            for (int r = 0; r < 4; ++r)
                #pragma unroll
                for (int j = 0; j < 16; ++j)
                    acc[r][j] = fmaf(av[r], w[j], acc[r][j]);
        }
    }
    float part[4];
    #pragma unroll
    for (int r = 0; r < 4; ++r) {
        float s = 0.f;
        #pragma unroll
        for (int j = 0; j < 16; ++j)
            s += fmaxf(acc[r][j] + bl2[c0 + j], 0.f) * w3l[c0 + j];
        part[r] = s;
    }
    #pragma unroll
    for (int off = 1; off < 8; off <<= 1)
        #pragma unroll
        for (int r = 0; r < 4; ++r) part[r] += __shfl_xor(part[r], off);
    if (cc == 0) {
        float bb = bl3[0];
        #pragma unroll
        for (int r = 0; r < 4; ++r) out[g0 + rg * 4 + r] = part[r] + bb;
    }
}

// ---------------- launch ----------------

extern "C" void kernel_launch(void* const* d_in, const int* in_sizes, int n_in,
                              void* d_out, int out_size, void* d_ws, size_t ws_size,
                              hipStream_t stream) {
    const float* x     = (const float*)d_in[0];
    const int*   ei    = (const int*)d_in[1];
    const int*   batch = (const int*)d_in[2];
    const float* W1  = (const float*)d_in[3];  const float* b1  = (const float*)d_in[4];
    const float* W2  = (const float*)d_in[5];  const float* b2  = (const float*)d_in[6];
    const float* W3  = (const float*)d_in[7];  const float* b3  = (const float*)d_in[8];
    const float* Wl1 = (const float*)d_in[9];  const float* bl1 = (const float*)d_in[10];
    const float* Wl2 = (const float*)d_in[11]; const float* bl2 = (const float*)d_in[12];
    const float* Wl3 = (const float*)d_in[13]; const float* bl3 = (const float*)d_in[14];

    const int N = in_sizes[0];
    const int E = in_sizes[1] / 2;
    const int G = out_size;
    const int* srcp = ei;
    const int* dstp = ei + E;
    const int NB = (N + BN - 1) / BN;

    char* w = (char*)d_ws;
    size_t off = 0;
    auto alloc = [&](size_t bytes) -> void* {
        void* p = w + off;
        off += (bytes + 255) & ~(size_t)255;
        return p;
    };
    int*    coarse = (int*)alloc((size_t)MAXNB * 4);
    int*    cbase  = (int*)alloc((size_t)(MAXNB + 1) * 4);
    int*    gcur   = (int*)alloc((size_t)MAXNB * 4);
    int*    offs   = (int*)alloc((size_t)(N + 1) * 4);
    int*    csr    = (int*)alloc((size_t)E * 4);
    float*  dinv   = (float*)alloc((size_t)N * 4);
    float*  sbuf   = (float*)alloc((size_t)N * 4);
    float2* td     = (float2*)alloc((size_t)N * 8);
    float*  A      = (float*)alloc((size_t)N * H * 4);   // Z2
    float*  B      = (float*)alloc((size_t)N * H * 4);   // pairbuf, then h3
    float*  P      = (float*)alloc((size_t)G * H * 4);   // pooled means
    unsigned* pairbuf = (unsigned*)B;   // alias: dead before agg_gemm3 writes h3
    (void)ws_size; (void)n_in;

    // --- graph build ---
    hipMemsetAsync(coarse, 0, (size_t)MAXNB * 4, stream);
    hist_coarse_k<<<256, 256, 0, stream>>>(dstp, coarse, E, NB);
    scan_coarse_k<<<1, 1, 0, stream>>>(coarse, cbase, gcur, offs, NB, N, E);
    scatter_pairs_k<<<(E + CHUNK - 1) / CHUNK, 256, 0, stream>>>(srcp, dstp, gcur, pairbuf, E, NB);
    build_csr_k<<<NB, 512, 0, stream>>>(pairbuf, cbase, offs, dinv, csr, N);

    // --- layer 1 (scalar feature) ---
    s_k<<<(N + 255) / 256, 256, 0, stream>>>(x, dinv, sbuf, N);
    agg1_k<<<(N + 255) / 256, 256, 0, stream>>>(sbuf, offs, csr, dinv, td, N);

    // --- layer 2: fused scalar-aggregate + GEMM(W2) ---
    l2_fused_k<<<(N + TILE - 1) / TILE, 256, 0, stream>>>(td, offs, csr, W1, b1, W2, b2, dinv, A, N);

    // --- layer 3: fused row-gather + GEMM(W3) ---
    agg_gemm3_k<<<(N + TILE - 1) / TILE, 256, 0, stream>>>(A, offs, csr, dinv, W3, b3, B, N);

    // --- pool + MLP head ---
    pool_k<<<G, 128, 0, stream>>>(B, batch, P, N, G);
    head_k<<<(G + 127) / 128, 256, 0, stream>>>(P, Wl1, bl1, Wl2, bl2, Wl3, bl3,
                                                (float*)d_out, G);
}

// Round 8
// 803.434 us; speedup vs baseline: 1.3593x; 1.3593x over previous
//
#include <hip/hip_runtime.h>

#define H 128
#define SHIFT 9             // nodes per coarse bucket = 512
#define BN 512
#define MAXNB 256           // max coarse buckets (N <= 131072)
#define CHUNK 4096          // edges per scatter block
#define CSTRIDE (H * 16 + 4)   // 2052 floats: per-cc transposed W block, conflict-free

// ============ graph build: two-level counting sort (no random 4B scatters) ============

__global__ __launch_bounds__(256) void hist_coarse_k(const int* __restrict__ dst,
                                                     int* __restrict__ coarse, int E, int NBv) {
    __shared__ int h[MAXNB];
    int tid = threadIdx.x;
    h[tid] = 0;
    if (tid + 256 < MAXNB) h[tid + 256] = 0;
    __syncthreads();
    for (int e = blockIdx.x * blockDim.x + tid; e < E; e += gridDim.x * blockDim.x)
        atomicAdd(&h[dst[e] >> SHIFT], 1);
    __syncthreads();
    if (tid < NBv && h[tid] > 0) atomicAdd(&coarse[tid], h[tid]);
    if (tid + 256 < NBv && h[tid + 256] > 0) atomicAdd(&coarse[tid + 256], h[tid + 256]);
}

__global__ void scan_coarse_k(const int* __restrict__ coarse, int* __restrict__ cbase,
                              int* __restrict__ gcur, int* __restrict__ offs,
                              int NBv, int N, int E) {
    if (blockIdx.x == 0 && threadIdx.x == 0) {
        int run = 0;
        for (int b = 0; b < NBv; ++b) { int v = coarse[b]; cbase[b] = run; gcur[b] = run; run += v; }
        cbase[NBv] = run;
        offs[N] = E;
    }
}

__global__ __launch_bounds__(256) void scatter_pairs_k(const int* __restrict__ src,
                                                       const int* __restrict__ dst,
                                                       int* __restrict__ gcur,
                                                       unsigned* __restrict__ pairbuf,
                                                       int E, int NBv) {
    __shared__ unsigned stage[CHUNK];
    __shared__ unsigned char stb[CHUNK];
    __shared__ int hist[MAXNB], basel[MAXNB], cur[MAXNB], gbase[MAXNB];
    __shared__ int total;
    int tid = threadIdx.x;
    int base = blockIdx.x * CHUNK;

    int mysrc[16], mydst[16];
    #pragma unroll
    for (int i = 0; i < 16; ++i) {
        int e = base + i * 256 + tid;
        if (e < E) { mysrc[i] = src[e]; mydst[i] = dst[e]; } else mydst[i] = -1;
    }
    hist[tid] = 0; hist[tid + 256] = 0;
    __syncthreads();
    #pragma unroll
    for (int i = 0; i < 16; ++i)
        if (mydst[i] >= 0) atomicAdd(&hist[mydst[i] >> SHIFT], 1);
    __syncthreads();
    if (tid == 0) {
        int run = 0;
        for (int b = 0; b < NBv; ++b) { basel[b] = run; run += hist[b]; }
        total = run;
    }
    __syncthreads();
    for (int b = tid; b < NBv; b += 256) {
        cur[b] = basel[b];
        if (hist[b] > 0) gbase[b] = atomicAdd(&gcur[b], hist[b]);
    }
    __syncthreads();
    #pragma unroll
    for (int i = 0; i < 16; ++i)
        if (mydst[i] >= 0) {
            int b = mydst[i] >> SHIFT;
            int slot = atomicAdd(&cur[b], 1);
            stage[slot] = ((unsigned)(mydst[i] & (BN - 1)) << 17) | (unsigned)mysrc[i];
            stb[slot] = (unsigned char)b;
        }
    __syncthreads();
    for (int s = tid; s < total; s += 256) {
        int b = stb[s];
        pairbuf[gbase[b] + (s - basel[b])] = stage[s];
    }
}

__global__ __launch_bounds__(512) void build_csr_k(const unsigned* __restrict__ pairbuf,
                                                   const int* __restrict__ cbase,
                                                   int* __restrict__ offs, float* __restrict__ dinv,
                                                   int* __restrict__ csr, int N) {
    __shared__ int hist[BN];
    __shared__ int cur[BN];
    __shared__ int ps[BN];
    int b = blockIdx.x, tid = threadIdx.x;
    int node0 = b << SHIFT;
    int e0 = cbase[b], e1 = cbase[b + 1];
    hist[tid] = 0;
    __syncthreads();
    for (int p = e0 + tid; p < e1; p += 512)
        atomicAdd(&hist[pairbuf[p] >> 17], 1);
    __syncthreads();
    int v0 = hist[tid];
    ps[tid] = v0;
    __syncthreads();
    for (int off = 1; off < BN; off <<= 1) {
        int t = (tid >= off) ? ps[tid - off] : 0;
        __syncthreads();
        ps[tid] += t;
        __syncthreads();
    }
    int g0 = e0 + ps[tid] - v0;
    int n0 = node0 + tid;
    if (n0 < N) { offs[n0] = g0; dinv[n0] = rsqrtf((float)(v0 + 1)); }
    cur[tid] = g0;
    __syncthreads();
    for (int p = e0 + tid; p < e1; p += 512) {
        unsigned v = pairbuf[p];
        int pos = atomicAdd(&cur[v >> 17], 1);
        csr[pos] = (int)(v & 0x1FFFFu);
    }
}

// ---------------- layer 1 (scalar input feature) ----------------

__global__ void s_k(const float* __restrict__ x, const float* __restrict__ dinv,
                    float* __restrict__ s, int n) {
    int i = blockIdx.x * blockDim.x + threadIdx.x;
    if (i < n) s[i] = x[i] * dinv[i];
}

// t_i = dinv_i*(s_i + sum s_src); emits packed (t, dinv) pairs
__global__ void agg1_k(const float* __restrict__ s, const int* __restrict__ offs,
                       const int* __restrict__ csr, const float* __restrict__ dinv,
                       float2* __restrict__ td, int n) {
    int i = blockIdx.x * blockDim.x + threadIdx.x;
    if (i >= n) return;
    float sum = s[i];
    int e0 = offs[i], e1 = offs[i + 1];
    float a0 = 0.f, a1 = 0.f, a2 = 0.f, a3 = 0.f;
    int p = e0;
    for (; p + 4 <= e1; p += 4) {
        a0 += s[csr[p]]; a1 += s[csr[p + 1]]; a2 += s[csr[p + 2]]; a3 += s[csr[p + 3]];
    }
    for (; p < e1; ++p) sum += s[csr[p]];
    sum += (a0 + a1) + (a2 + a3);
    float d = dinv[i];
    td[i] = make_float2(sum * d, d);
}

// ------- layer-2 fused aggregation over SCALARS (aggregate-then-GEMM algebra) -------
// U2_i = dinv_i * sum_{j in N(i)+self} dinv_j * relu(t_j*w1 + b1)

__global__ __launch_bounds__(256) void l2_agg_k(const float2* __restrict__ td,
                                                const int* __restrict__ offs,
                                                const int* __restrict__ csr,
                                                const float* __restrict__ w1,
                                                const float* __restrict__ b1,
                                                float* __restrict__ U, int n) {
    int node = blockIdx.x * 4 + (threadIdx.x >> 6);
    int lane = threadIdx.x & 63;
    if (node >= n) return;
    float wa = w1[lane],      wb = w1[lane + 64];
    float ba = b1[lane],      bb = b1[lane + 64];
    float2 self = td[node];
    float sa = fmaxf(fmaf(self.x, wa, ba), 0.f) * self.y;
    float sb = fmaxf(fmaf(self.x, wb, bb), 0.f) * self.y;
    int e0 = offs[node], e1 = offs[node + 1];
    int p = e0;
    for (; p + 8 <= e1; p += 8) {
        float2 v[8];
        #pragma unroll
        for (int u = 0; u < 8; ++u) v[u] = td[csr[p + u]];
        #pragma unroll
        for (int u = 0; u < 8; ++u) {
            sa = fmaf(fmaxf(fmaf(v[u].x, wa, ba), 0.f), v[u].y, sa);
            sb = fmaf(fmaxf(fmaf(v[u].x, wb, bb), 0.f), v[u].y, sb);
        }
    }
    for (; p < e1; ++p) {
        float2 v = td[csr[p]];
        sa = fmaf(fmaxf(fmaf(v.x, wa, ba), 0.f), v.y, sa);
        sb = fmaf(fmaxf(fmaf(v.x, wb, bb), 0.f), v.y, sb);
    }
    float d = self.y;
    U[(size_t)node * H + lane]      = sa * d;
    U[(size_t)node * H + lane + 64] = sb * d;
}

// ---- conflict-free W staging: WT[cc][k][j], stride CSTRIDE per cc ----

__device__ __forceinline__ void stage_WT(const float* __restrict__ W, float* __restrict__ WT) {
    for (int idx = threadIdx.x; idx < H * H / 4; idx += 256) {
        float4 v = ((const float4*)W)[idx];
        int k  = idx >> 5;
        int c4 = idx & 31;
        int cc = c4 >> 2;
        int j  = (c4 & 3) * 4;
        *(float4*)(WT + cc * CSTRIDE + k * 16 + j) = v;
    }
}

// ------- GEMM: Z2s = sliceMajor( pscale[row] * relu(in@W + bias) ) -------
// slice-major output: Zs[s][row][0..8) with s = col/8 (16 slices), each slice contiguous N*8 floats

__global__ __launch_bounds__(256) void gemm_post_k(const float* __restrict__ in, const float* __restrict__ W,
                                                   const float* __restrict__ bias, const float* __restrict__ pscale,
                                                   float* __restrict__ Zs, int n) {
    __shared__ float WT[8 * CSTRIDE];
    stage_WT(W, WT);
    __syncthreads();
    const int cc = threadIdx.x & 7;
    const int rg = threadIdx.x >> 3;
    const int c0 = cc * 16;
    const int row0 = blockIdx.x * 128 + rg * 4;
    const float* wt = WT + cc * CSTRIDE;
    const size_t n8 = (size_t)n * 8;

    const float* p[4];
    #pragma unroll
    for (int r = 0; r < 4; ++r) {
        int rr = row0 + r; if (rr > n - 1) rr = n - 1;
        p[r] = in + (size_t)rr * H;
    }

    float acc[4][16];
    #pragma unroll
    for (int r = 0; r < 4; ++r)
        #pragma unroll
        for (int j = 0; j < 16; ++j) acc[r][j] = 0.f;

    for (int k4 = 0; k4 < H / 4; ++k4) {
        float4 a[4];
        #pragma unroll
        for (int r = 0; r < 4; ++r) a[r] = *(const float4*)(p[r] + k4 * 4);
        #pragma unroll
        for (int kk = 0; kk < 4; ++kk) {
            const float* wb = wt + (k4 * 4 + kk) * 16;
            float w[16];
            *(float4*)(w + 0)  = *(const float4*)(wb + 0);
            *(float4*)(w + 4)  = *(const float4*)(wb + 4);
            *(float4*)(w + 8)  = *(const float4*)(wb + 8);
            *(float4*)(w + 12) = *(const float4*)(wb + 12);
            float av[4];
            #pragma unroll
            for (int r = 0; r < 4; ++r) av[r] = ((const float*)&a[r])[kk];
            #pragma unroll
            for (int r = 0; r < 4; ++r)
                #pragma unroll
                for (int j = 0; j < 16; ++j)
                    acc[r][j] = fmaf(av[r], w[j], acc[r][j]);
        }
    }

    const int s0 = cc * 2;
    #pragma unroll
    for (int r = 0; r < 4; ++r) {
        int row = row0 + r;
        if (row < n) {
            float sc = pscale[row];
            float o[16];
            #pragma unroll
            for (int j = 0; j < 16; ++j)
                o[j] = fmaxf(acc[r][j] + bias[c0 + j], 0.f) * sc;
            float* z0 = Zs + (size_t)s0 * n8 + (size_t)row * 8;
            float* z1 = z0 + n8;
            *(float4*)(z0 + 0) = *(float4*)(o + 0);
            *(float4*)(z0 + 4) = *(float4*)(o + 4);
            *(float4*)(z1 + 0) = *(float4*)(o + 8);
            *(float4*)(z1 + 4) = *(float4*)(o + 12);
        }
    }
}

// ======= layer-3 aggregation, XCD-sliced: each block handles ONE 8-col slice over a node range =======
// slice = blockIdx%8 (+8 in phase 2) -> same slice pins to same XCD's L2 (3.2 MB working set).
// U3s[s][i][0..8) = dinv_i * (Zs[s][i] + sum_{src} Zs[s][src])

__global__ __launch_bounds__(256) void agg_slice_k(const float* __restrict__ Zs,
                                                   const int* __restrict__ offs,
                                                   const int* __restrict__ csr,
                                                   const float* __restrict__ dinv,
                                                   float* __restrict__ Us,
                                                   int n, int BP) {
    int b = blockIdx.x;
    int phase = b / (8 * BP);
    int within = b - phase * 8 * BP;
    int slice = (within & 7) + 8 * phase;
    int rblk = within >> 3;
    int wave = threadIdx.x >> 6;
    int lane = threadIdx.x & 63;
    int slot = lane >> 1;           // 32 edge slots
    int hlf  = lane & 1;            // 2 x float4 per row-slice
    size_t sbase = (size_t)slice * n * 8;
    const float* Zsl = Zs + sbase;
    float* Usl = Us + sbase;

    int node0 = rblk * 256 + wave * 64;
    int nodeEnd = node0 + 64; if (nodeEnd > n) nodeEnd = n;
    for (int node = node0; node < nodeEnd; ++node) {
        int e0 = offs[node], e1 = offs[node + 1];
        float4 acc = make_float4(0.f, 0.f, 0.f, 0.f);
        if (lane < 2) acc = *(const float4*)(Zsl + (size_t)node * 8 + hlf * 4);  // self loop
        for (int q = e0; q < e1; q += 32) {
            int e = q + slot;
            if (e < e1) {
                int srcn = csr[e];
                float4 v = *(const float4*)(Zsl + (size_t)srcn * 8 + hlf * 4);
                acc.x += v.x; acc.y += v.y; acc.z += v.z; acc.w += v.w;
            }
        }
        #pragma unroll
        for (int off = 2; off < 64; off <<= 1) {
            acc.x += __shfl_xor(acc.x, off);
            acc.y += __shfl_xor(acc.y, off);
            acc.z += __shfl_xor(acc.z, off);
            acc.w += __shfl_xor(acc.w, off);
        }
        if (lane < 2) {
            float d = dinv[node];
            *(float4*)(Usl + (size_t)node * 8 + hlf * 4) =
                make_float4(acc.x * d, acc.y * d, acc.z * d, acc.w * d);
        }
    }
}

// ------- layer-3 GEMM: h3 = relu(U3s@W3 + b3); A read slice-major, out row-major -------

__global__ __launch_bounds__(256) void gemm_k(const float* __restrict__ As, const float* __restrict__ W,
                                              const float* __restrict__ bias,
                                              float* __restrict__ out, int n) {
    __shared__ float WT[8 * CSTRIDE];
    stage_WT(W, WT);
    __syncthreads();
    const int cc = threadIdx.x & 7;
    const int rg = threadIdx.x >> 3;
    const int c0 = cc * 16;
    const int row0 = blockIdx.x * 128 + rg * 4;
    const float* wt = WT + cc * CSTRIDE;
    const size_t n8 = (size_t)n * 8;

    size_t r8[4];
    #pragma unroll
    for (int r = 0; r < 4; ++r) {
        int rr = row0 + r; if (rr > n - 1) rr = n - 1;
        r8[r] = (size_t)rr * 8;
    }

    float acc[4][16];
    #pragma unroll
    for (int r = 0; r < 4; ++r)
        #pragma unroll
        for (int j = 0; j < 16; ++j) acc[r][j] = 0.f;

    for (int k4 = 0; k4 < H / 4; ++k4) {
        const float* sb = As + (size_t)(k4 >> 1) * n8 + (k4 & 1) * 4;
        float4 a[4];
        #pragma unroll
        for (int r = 0; r < 4; ++r) a[r] = *(const float4*)(sb + r8[r]);
        #pragma unroll
        for (int kk = 0; kk < 4; ++kk) {
            const float* wb = wt + (k4 * 4 + kk) * 16;
            float w[16];
            *(float4*)(w + 0)  = *(const float4*)(wb + 0);
            *(float4*)(w + 4)  = *(const float4*)(wb + 4);
            *(float4*)(w + 8)  = *(const float4*)(wb + 8);
            *(float4*)(w + 12) = *(const float4*)(wb + 12);
            float av[4];
            #pragma unroll
            for (int r = 0; r < 4; ++r) av[r] = ((const float*)&a[r])[kk];
            #pragma unroll
            for (int r = 0; r < 4; ++r)
                #pragma unroll
                for (int j = 0; j < 16; ++j)
                    acc[r][j] = fmaf(av[r], w[j], acc[r][j]);
        }
    }

    #pragma unroll
    for (int r = 0; r < 4; ++r) {
        int row = row0 + r;
        if (row < n) {
            float* orow = out + (size_t)row * H + c0;
            #pragma unroll
            for (int j4 = 0; j4 < 4; ++j4) {
                float4 o;
                o.x = fmaxf(acc[r][j4 * 4 + 0] + bias[c0 + j4 * 4 + 0], 0.f);
                o.y = fmaxf(acc[r][j4 * 4 + 1] + bias[c0 + j4 * 4 + 1], 0.f);
                o.z = fmaxf(acc[r][j4 * 4 + 2] + bias[c0 + j4 * 4 + 2], 0.f);
                o.w = fmaxf(acc[r][j4 * 4 + 3] + bias[c0 + j4 * 4 + 3], 0.f);
                *(float4*)(orow + j4 * 4) = o;
            }
        }
    }
}

// ---------------- pooling (binary search over sorted batch ids; overwrite, no atomics) --------

__global__ __launch_bounds__(128) void pool_k(const float* __restrict__ h, const int* __restrict__ batch,
                                              float* __restrict__ P, int n, int G) {
    int g = blockIdx.x, f = threadIdx.x;
    int lo = 0, hi = n;
    while (lo < hi) { int m = (lo + hi) >> 1; if (batch[m] < g) lo = m + 1; else hi = m; }
    int s0 = lo;
    hi = n;
    while (lo < hi) { int m = (lo + hi) >> 1; if (batch[m] < g + 1) lo = m + 1; else hi = m; }
    int s1 = lo;
    float a0 = 0.f, a1 = 0.f, a2 = 0.f, a3 = 0.f;
    int i = s0;
    for (; i + 4 <= s1; i += 4) {
        a0 += h[(size_t)i * H + f];
        a1 += h[(size_t)(i + 1) * H + f];
        a2 += h[(size_t)(i + 2) * H + f];
        a3 += h[(size_t)(i + 3) * H + f];
    }
    for (; i < s1; ++i) a0 += h[(size_t)i * H + f];
    float sum = (a0 + a1) + (a2 + a3);
    float c = (float)(s1 - s0); if (c < 1.f) c = 1.f;
    P[(size_t)g * H + f] = sum / c;
}

// ------- fused MLP head -------

__global__ __launch_bounds__(256) void head_k(const float* __restrict__ P,
                                              const float* __restrict__ Wl1, const float* __restrict__ bl1,
                                              const float* __restrict__ Wl2, const float* __restrict__ bl2,
                                              const float* __restrict__ Wl3, const float* __restrict__ bl3,
                                              float* __restrict__ out, int G) {
    __shared__ float Wb[H * H];
    __shared__ float Tl[H * 133];
    __shared__ float w3l[H];
    int tid = threadIdx.x;
    int g0 = blockIdx.x * 128;

    if (tid < 128) w3l[tid] = Wl3[tid];
    for (int i = tid; i < H * H / 4; i += 256) ((float4*)Wb)[i] = ((const float4*)Wl1)[i];
    __syncthreads();

    const int cc = tid & 7, rg = tid >> 3, c0 = cc * 16;
    float acc[4][16];

    #pragma unroll
    for (int r = 0; r < 4; ++r)
        #pragma unroll
        for (int j = 0; j < 16; ++j) acc[r][j] = 0.f;
    const float4* P4 = (const float4*)P;
    for (int k4 = 0; k4 < H / 4; ++k4) {
        float4 a[4];
        #pragma unroll
        for (int r = 0; r < 4; ++r) a[r] = P4[(size_t)(g0 + rg * 4 + r) * 32 + k4];
        const float* wbase = Wb + (k4 * 4) * H + c0;
        #pragma unroll
        for (int kk = 0; kk < 4; ++kk) {
            float w[16];
            *(float4*)(w + 0)  = *(const float4*)(wbase + kk * H + 0);
            *(float4*)(w + 4)  = *(const float4*)(wbase + kk * H + 4);
            *(float4*)(w + 8)  = *(const float4*)(wbase + kk * H + 8);
            *(float4*)(w + 12) = *(const float4*)(wbase + kk * H + 12);
            float av[4];
            #pragma unroll
            for (int r = 0; r < 4; ++r) av[r] = ((const float*)&a[r])[kk];
            #pragma unroll
            for (int r = 0; r < 4; ++r)
                #pragma unroll
                for (int j = 0; j < 16; ++j)
                    acc[r][j] = fmaf(av[r], w[j], acc[r][j]);
        }
    }
    #pragma unroll
    for (int r = 0; r < 4; ++r) {
        int rl = rg * 4 + r;
        #pragma unroll
        for (int j = 0; j < 16; ++j)
            Tl[rl * 133 + c0 + j] = fmaxf(acc[r][j] + bl1[c0 + j], 0.f);
    }
    __syncthreads();
    for (int i = tid; i < H * H / 4; i += 256) ((float4*)Wb)[i] = ((const float4*)Wl2)[i];
    __syncthreads();

    #pragma unroll
    for (int r = 0; r < 4; ++r)
        #pragma unroll
        for (int j = 0; j < 16; ++j) acc[r][j] = 0.f;
    for (int k4 = 0; k4 < H / 4; ++k4) {
        float4 a[4];
        #pragma unroll
        for (int r = 0; r < 4; ++r) a[r] = *(const float4*)(Tl + (rg * 4 + r) * 133 + k4 * 4);
        const float* wbase = Wb + (k4 * 4) * H + c0;
        #pragma unroll
        for (int kk = 0; kk < 4; ++kk) {
            float w[16];
            *(float4*)(w + 0)  = *(const float4*)(wbase + kk * H + 0);
            *(float4*)(w + 4)  = *(const float4*)(wbase + kk * H + 4);
            *(float4*)(w + 8)  = *(const float4*)(wbase + kk * H + 8);
            *(float4*)(w + 12) = *(const float4*)(wbase + kk * H + 12);
            float av[4];
            #pragma unroll
            for (int r = 0; r < 4; ++r) av[r] = ((const float*)&a[r])[kk];
            #pragma unroll
            for (int r = 0; r < 4; ++r)
                #pragma unroll
                for (int j = 0; j < 16; ++j)
                    acc[r][j] = fmaf(av[r], w[j], acc[r][j]);
        }
    }
    float part[4];
    #pragma unroll
    for (int r = 0; r < 4; ++r) {
        float s = 0.f;
        #pragma unroll
        for (int j = 0; j < 16; ++j)
            s += fmaxf(acc[r][j] + bl2[c0 + j], 0.f) * w3l[c0 + j];
        part[r] = s;
    }
    #pragma unroll
    for (int off = 1; off < 8; off <<= 1)
        #pragma unroll
        for (int r = 0; r < 4; ++r) part[r] += __shfl_xor(part[r], off);
    if (cc == 0) {
        float bb = bl3[0];
        #pragma unroll
        for (int r = 0; r < 4; ++r) out[g0 + rg * 4 + r] = part[r] + bb;
    }
}

// ---------------- launch ----------------

extern "C" void kernel_launch(void* const* d_in, const int* in_sizes, int n_in,
                              void* d_out, int out_size, void* d_ws, size_t ws_size,
                              hipStream_t stream) {
    const float* x     = (const float*)d_in[0];
    const int*   ei    = (const int*)d_in[1];
    const int*   batch = (const int*)d_in[2];
    const float* W1  = (const float*)d_in[3];  const float* b1  = (const float*)d_in[4];
    const float* W2  = (const float*)d_in[5];  const float* b2  = (const float*)d_in[6];
    const float* W3  = (const float*)d_in[7];  const float* b3  = (const float*)d_in[8];
    const float* Wl1 = (const float*)d_in[9];  const float* bl1 = (const float*)d_in[10];
    const float* Wl2 = (const float*)d_in[11]; const float* bl2 = (const float*)d_in[12];
    const float* Wl3 = (const float*)d_in[13]; const float* bl3 = (const float*)d_in[14];

    const int N = in_sizes[0];
    const int E = in_sizes[1] / 2;
    const int G = out_size;
    const int* srcp = ei;
    const int* dstp = ei + E;
    const int NB = (N + BN - 1) / BN;
    const int BP = (N + 255) / 256;      // node-range blocks per slice

    char* w = (char*)d_ws;
    size_t off = 0;
    auto alloc = [&](size_t bytes) -> void* {
        void* p = w + off;
        off += (bytes + 255) & ~(size_t)255;
        return p;
    };
    int*    coarse = (int*)alloc((size_t)MAXNB * 4);
    int*    cbase  = (int*)alloc((size_t)(MAXNB + 1) * 4);
    int*    gcur   = (int*)alloc((size_t)MAXNB * 4);
    int*    offs   = (int*)alloc((size_t)(N + 1) * 4);
    int*    csr    = (int*)alloc((size_t)E * 4);
    float*  dinv   = (float*)alloc((size_t)N * 4);
    float*  sbuf   = (float*)alloc((size_t)N * 4);
    float2* td     = (float2*)alloc((size_t)N * 8);
    float*  A      = (float*)alloc((size_t)N * H * 4);   // U2 (row-major), then U3s (slice-major)
    float*  B      = (float*)alloc((size_t)N * H * 4);   // pairbuf, then Z2s (slice-major), then h3
    float*  P      = (float*)alloc((size_t)G * H * 4);   // pooled means
    unsigned* pairbuf = (unsigned*)B;   // alias: dead before gemm_post writes Z2s
    (void)ws_size; (void)n_in;

    // --- graph build ---
    hipMemsetAsync(coarse, 0, (size_t)MAXNB * 4, stream);
    hist_coarse_k<<<256, 256, 0, stream>>>(dstp, coarse, E, NB);
    scan_coarse_k<<<1, 1, 0, stream>>>(coarse, cbase, gcur, offs, NB, N, E);
    scatter_pairs_k<<<(E + CHUNK - 1) / CHUNK, 256, 0, stream>>>(srcp, dstp, gcur, pairbuf, E, NB);
    build_csr_k<<<NB, 512, 0, stream>>>(pairbuf, cbase, offs, dinv, csr, N);

    // --- layer 1 (scalar feature) ---
    s_k<<<(N + 255) / 256, 256, 0, stream>>>(x, dinv, sbuf, N);
    agg1_k<<<(N + 255) / 256, 256, 0, stream>>>(sbuf, offs, csr, dinv, td, N);

    // --- layer 2: scalar-gather fused aggregation, then GEMM (slice-major out) ---
    l2_agg_k<<<(N + 3) / 4, 256, 0, stream>>>(td, offs, csr, W1, b1, A, N);
    gemm_post_k<<<(N + 127) / 128, 256, 0, stream>>>(A, W2, b2, dinv, B, N);   // B = Z2s

    // --- layer 3: XCD-sliced row gather, then GEMM, pool ---
    agg_slice_k<<<16 * BP, 256, 0, stream>>>(B, offs, csr, dinv, A, N, BP);    // A = U3s
    gemm_k<<<(N + 127) / 128, 256, 0, stream>>>(A, W3, b3, B, N);              // B = h3
    pool_k<<<G, 128, 0, stream>>>(B, batch, P, N, G);

    // --- fused MLP head ---
    head_k<<<(G + 127) / 128, 256, 0, stream>>>(P, Wl1, bl1, Wl2, bl2, Wl3, bl3,
                                                (float*)d_out, G);
}

// Round 9
// 581.105 us; speedup vs baseline: 1.8793x; 1.3826x over previous
//
#include <hip/hip_runtime.h>

#define H 128
#define SHIFT 9             // nodes per coarse bucket = 512
#define BN 512
#define MAXNB 256           // max coarse buckets (N <= 131072)
#define CHUNK 4096          // edges per scatter block
#define CSTRIDE (H * 16 + 4)   // 2052 floats: per-cc transposed W block, conflict-free
#define PG 16               // graphs per block tracked in LDS pool partial

// ============ graph build: two-level counting sort (no random 4B scatters) ============

__global__ __launch_bounds__(256) void hist_coarse_k(const int* __restrict__ dst,
                                                     int* __restrict__ coarse, int E, int NBv) {
    __shared__ int h[MAXNB];
    int tid = threadIdx.x;
    h[tid] = 0;
    __syncthreads();
    for (int e = blockIdx.x * blockDim.x + tid; e < E; e += gridDim.x * blockDim.x)
        atomicAdd(&h[dst[e] >> SHIFT], 1);
    __syncthreads();
    if (tid < NBv && h[tid] > 0) atomicAdd(&coarse[tid], h[tid]);
}

// one block, 256 threads: exclusive scan of coarse -> cbase/gcur; also offs[N]=E
__global__ __launch_bounds__(256) void scan_coarse_k(const int* __restrict__ coarse, int* __restrict__ cbase,
                                                     int* __restrict__ gcur, int* __restrict__ offs,
                                                     int NBv, int N, int E) {
    __shared__ int sm[256];
    int tid = threadIdx.x;
    int v = (tid < NBv) ? coarse[tid] : 0;
    sm[tid] = v;
    __syncthreads();
    for (int off = 1; off < 256; off <<= 1) {
        int t = (tid >= off) ? sm[tid - off] : 0;
        __syncthreads();
        sm[tid] += t;
        __syncthreads();
    }
    int excl = sm[tid] - v;
    if (tid < NBv) { cbase[tid] = excl; gcur[tid] = excl; }
    if (tid == NBv - 1) cbase[NBv] = excl + v;
    if (tid == 0) offs[N] = E;
}

__global__ __launch_bounds__(256) void scatter_pairs_k(const int* __restrict__ src,
                                                       const int* __restrict__ dst,
                                                       int* __restrict__ gcur,
                                                       unsigned* __restrict__ pairbuf,
                                                       int E, int NBv) {
    __shared__ unsigned stage[CHUNK];
    __shared__ unsigned char stb[CHUNK];
    __shared__ int hist[MAXNB], basel[MAXNB], cur[MAXNB], gbase[MAXNB];
    __shared__ int total;
    int tid = threadIdx.x;
    int base = blockIdx.x * CHUNK;

    int mysrc[16], mydst[16];
    #pragma unroll
    for (int i = 0; i < 16; ++i) {
        int e = base + i * 256 + tid;
        if (e < E) { mysrc[i] = src[e]; mydst[i] = dst[e]; } else mydst[i] = -1;
    }
    hist[tid] = 0;
    __syncthreads();
    #pragma unroll
    for (int i = 0; i < 16; ++i)
        if (mydst[i] >= 0) atomicAdd(&hist[mydst[i] >> SHIFT], 1);
    __syncthreads();
    if (tid == 0) {
        int run = 0;
        for (int b = 0; b < NBv; ++b) { basel[b] = run; run += hist[b]; }
        total = run;
    }
    __syncthreads();
    if (tid < NBv) {
        cur[tid] = basel[tid];
        if (hist[tid] > 0) gbase[tid] = atomicAdd(&gcur[tid], hist[tid]);
    }
    __syncthreads();
    #pragma unroll
    for (int i = 0; i < 16; ++i)
        if (mydst[i] >= 0) {
            int b = mydst[i] >> SHIFT;
            int slot = atomicAdd(&cur[b], 1);
            stage[slot] = ((unsigned)(mydst[i] & (BN - 1)) << 17) | (unsigned)mysrc[i];
            stb[slot] = (unsigned char)b;
        }
    __syncthreads();
    for (int s = tid; s < total; s += 256) {
        int b = stb[s];
        pairbuf[gbase[b] + (s - basel[b])] = stage[s];
    }
}

// one block per coarse bucket: LDS hist + scan -> offs/dinv/s, then in-bucket scatter
__global__ __launch_bounds__(512) void build_csr_k(const unsigned* __restrict__ pairbuf,
                                                   const int* __restrict__ cbase,
                                                   const float* __restrict__ x,
                                                   int* __restrict__ offs, float* __restrict__ dinv,
                                                   float* __restrict__ s,
                                                   int* __restrict__ csr, int N) {
    __shared__ int hist[BN];
    __shared__ int cur[BN];
    __shared__ int ps[BN];
    int b = blockIdx.x, tid = threadIdx.x;
    int node0 = b << SHIFT;
    int e0 = cbase[b], e1 = cbase[b + 1];
    hist[tid] = 0;
    __syncthreads();
    for (int p = e0 + tid; p < e1; p += 512)
        atomicAdd(&hist[pairbuf[p] >> 17], 1);
    __syncthreads();
    int v0 = hist[tid];
    ps[tid] = v0;
    __syncthreads();
    for (int off = 1; off < BN; off <<= 1) {
        int t = (tid >= off) ? ps[tid - off] : 0;
        __syncthreads();
        ps[tid] += t;
        __syncthreads();
    }
    int g0 = e0 + ps[tid] - v0;
    int n0 = node0 + tid;
    if (n0 < N) {
        float d = rsqrtf((float)(v0 + 1));
        offs[n0] = g0;
        dinv[n0] = d;
        s[n0] = x[n0] * d;      // fused s_k
    }
    cur[tid] = g0;
    __syncthreads();
    for (int p = e0 + tid; p < e1; p += 512) {
        unsigned v = pairbuf[p];
        int pos = atomicAdd(&cur[v >> 17], 1);
        csr[pos] = (int)(v & 0x1FFFFu);
    }
}

// ---------------- layer 1: t_i = dinv_i*(s_i + sum s_src); emits (t, dinv) pairs ----------------

__global__ void agg1_k(const float* __restrict__ s, const int* __restrict__ offs,
                       const int* __restrict__ csr, const float* __restrict__ dinv,
                       float2* __restrict__ td, int n) {
    int i = blockIdx.x * blockDim.x + threadIdx.x;
    if (i >= n) return;
    float sum = s[i];
    int e0 = offs[i], e1 = offs[i + 1];
    float a0 = 0.f, a1 = 0.f, a2 = 0.f, a3 = 0.f;
    int p = e0;
    for (; p + 4 <= e1; p += 4) {
        a0 += s[csr[p]]; a1 += s[csr[p + 1]]; a2 += s[csr[p + 2]]; a3 += s[csr[p + 3]];
    }
    for (; p < e1; ++p) sum += s[csr[p]];
    sum += (a0 + a1) + (a2 + a3);
    float d = dinv[i];
    td[i] = make_float2(sum * d, d);
}

// ------- layer-2 fused aggregation over SCALARS (aggregate-then-GEMM algebra) -------
// U2_i = dinv_i * sum_{j in N(i)+self} dinv_j * relu(t_j*w1 + b1)

__global__ __launch_bounds__(256) void l2_agg_k(const float2* __restrict__ td,
                                                const int* __restrict__ offs,
                                                const int* __restrict__ csr,
                                                const float* __restrict__ w1,
                                                const float* __restrict__ b1,
                                                float* __restrict__ U, int n) {
    int node = blockIdx.x * 4 + (threadIdx.x >> 6);
    int lane = threadIdx.x & 63;
    if (node >= n) return;
    float wa = w1[lane],      wb = w1[lane + 64];
    float ba = b1[lane],      bb = b1[lane + 64];
    float2 self = td[node];
    float sa = fmaxf(fmaf(self.x, wa, ba), 0.f) * self.y;
    float sb = fmaxf(fmaf(self.x, wb, bb), 0.f) * self.y;
    int e0 = offs[node], e1 = offs[node + 1];
    int p = e0;
    for (; p + 8 <= e1; p += 8) {
        float2 v[8];
        #pragma unroll
        for (int u = 0; u < 8; ++u) v[u] = td[csr[p + u]];
        #pragma unroll
        for (int u = 0; u < 8; ++u) {
            sa = fmaf(fmaxf(fmaf(v[u].x, wa, ba), 0.f), v[u].y, sa);
            sb = fmaf(fmaxf(fmaf(v[u].x, wb, bb), 0.f), v[u].y, sb);
        }
    }
    for (; p < e1; ++p) {
        float2 v = td[csr[p]];
        sa = fmaf(fmaxf(fmaf(v.x, wa, ba), 0.f), v.y, sa);
        sb = fmaf(fmaxf(fmaf(v.x, wb, bb), 0.f), v.y, sb);
    }
    float d = self.y;
    U[(size_t)node * H + lane]      = sa * d;
    U[(size_t)node * H + lane + 64] = sb * d;
}

// ---- conflict-free W staging: WT[cc][k][j], stride CSTRIDE per cc ----

__device__ __forceinline__ void stage_WT(const float* __restrict__ W, float* __restrict__ WT) {
    for (int idx = threadIdx.x; idx < H * H / 4; idx += 256) {
        float4 v = ((const float4*)W)[idx];
        int k  = idx >> 5;
        int c4 = idx & 31;
        int cc = c4 >> 2;
        int j  = (c4 & 3) * 4;
        *(float4*)(WT + cc * CSTRIDE + k * 16 + j) = v;
    }
}

// ------- GEMM with post-activation row scale: Z2 = pscale[row] * relu(in@W + bias) -------

__global__ __launch_bounds__(256) void gemm_post_k(const float* __restrict__ in, const float* __restrict__ W,
                                                   const float* __restrict__ bias, const float* __restrict__ pscale,
                                                   float* __restrict__ out, int n) {
    __shared__ float WT[8 * CSTRIDE];
    stage_WT(W, WT);
    __syncthreads();
    const int cc = threadIdx.x & 7;
    const int rg = threadIdx.x >> 3;
    const int c0 = cc * 16;
    const int row0 = blockIdx.x * 128 + rg * 4;
    const float* wt = WT + cc * CSTRIDE;

    const float* p[4];
    #pragma unroll
    for (int r = 0; r < 4; ++r) {
        int rr = row0 + r; if (rr > n - 1) rr = n - 1;
        p[r] = in + (size_t)rr * H;
    }

    float acc[4][16];
    #pragma unroll
    for (int r = 0; r < 4; ++r)
        #pragma unroll
        for (int j = 0; j < 16; ++j) acc[r][j] = 0.f;

    for (int k4 = 0; k4 < H / 4; ++k4) {
        float4 a[4];
        #pragma unroll
        for (int r = 0; r < 4; ++r) a[r] = *(const float4*)(p[r] + k4 * 4);
        #pragma unroll
        for (int kk = 0; kk < 4; ++kk) {
            const float* wb = wt + (k4 * 4 + kk) * 16;
            float w[16];
            *(float4*)(w + 0)  = *(const float4*)(wb + 0);
            *(float4*)(w + 4)  = *(const float4*)(wb + 4);
            *(float4*)(w + 8)  = *(const float4*)(wb + 8);
            *(float4*)(w + 12) = *(const float4*)(wb + 12);
            float av[4];
            #pragma unroll
            for (int r = 0; r < 4; ++r) av[r] = ((const float*)&a[r])[kk];
            #pragma unroll
            for (int r = 0; r < 4; ++r)
                #pragma unroll
                for (int j = 0; j < 16; ++j)
                    acc[r][j] = fmaf(av[r], w[j], acc[r][j]);
        }
    }

    #pragma unroll
    for (int r = 0; r < 4; ++r) {
        int row = row0 + r;
        if (row < n) {
            float sc = pscale[row];
            float* orow = out + (size_t)row * H + c0;
            #pragma unroll
            for (int j4 = 0; j4 < 4; ++j4) {
                float4 o;
                o.x = fmaxf(acc[r][j4 * 4 + 0] + bias[c0 + j4 * 4 + 0], 0.f) * sc;
                o.y = fmaxf(acc[r][j4 * 4 + 1] + bias[c0 + j4 * 4 + 1], 0.f) * sc;
                o.z = fmaxf(acc[r][j4 * 4 + 2] + bias[c0 + j4 * 4 + 2], 0.f) * sc;
                o.w = fmaxf(acc[r][j4 * 4 + 3] + bias[c0 + j4 * 4 + 3], 0.f) * sc;
                *(float4*)(orow + j4 * 4) = o;
            }
        }
    }
}

// ------- whole-wave gather of one node's neighbor-row sum -------

__device__ __forceinline__ float4 gather_row_sum(const float4* __restrict__ hs4,
                                                 const int* __restrict__ csr,
                                                 int node, int e0, int e1, int half, int l) {
    float4 acc[8];
    #pragma unroll
    for (int u = 0; u < 8; ++u) acc[u] = make_float4(0.f, 0.f, 0.f, 0.f);
    if (half == 0) acc[0] = hs4[(size_t)node * 32 + l];   // self loop
    int q = e0;
    for (; q + 15 < e1; q += 16) {
        int idx[8];
        #pragma unroll
        for (int u = 0; u < 8; ++u) idx[u] = csr[q + 2 * u + half];
        #pragma unroll
        for (int u = 0; u < 8; ++u) {
            float4 v = hs4[(size_t)idx[u] * 32 + l];
            acc[u].x += v.x; acc[u].y += v.y; acc[u].z += v.z; acc[u].w += v.w;
        }
    }
    for (; q + 7 < e1; q += 8) {
        int idx[4];
        #pragma unroll
        for (int u = 0; u < 4; ++u) idx[u] = csr[q + 2 * u + half];
        #pragma unroll
        for (int u = 0; u < 4; ++u) {
            float4 v = hs4[(size_t)idx[u] * 32 + l];
            acc[u].x += v.x; acc[u].y += v.y; acc[u].z += v.z; acc[u].w += v.w;
        }
    }
    for (; q < e1; q += 2) {
        int off = q + half;
        if (off < e1) {
            float4 v = hs4[(size_t)csr[off] * 32 + l];
            acc[0].x += v.x; acc[0].y += v.y; acc[0].z += v.z; acc[0].w += v.w;
        }
    }
    float4 sum;
    sum.x = ((acc[0].x + acc[1].x) + (acc[2].x + acc[3].x)) + ((acc[4].x + acc[5].x) + (acc[6].x + acc[7].x));
    sum.y = ((acc[0].y + acc[1].y) + (acc[2].y + acc[3].y)) + ((acc[4].y + acc[5].y) + (acc[6].y + acc[7].y));
    sum.z = ((acc[0].z + acc[1].z) + (acc[2].z + acc[3].z)) + ((acc[4].z + acc[5].z) + (acc[6].z + acc[7].z));
    sum.w = ((acc[0].w + acc[1].w) + (acc[2].w + acc[3].w)) + ((acc[4].w + acc[5].w) + (acc[6].w + acc[7].w));
    sum.x += __shfl_xor(sum.x, 32);
    sum.y += __shfl_xor(sum.y, 32);
    sum.z += __shfl_xor(sum.z, 32);
    sum.w += __shfl_xor(sum.w, 32);
    return sum;
}

// ------- layer-3 aggregation of Z2 rows: U3_i = dinv_i * (Z2_i + sum Z2_src) -------

__global__ __launch_bounds__(256) void agg3_k(const float* __restrict__ Z, const int* __restrict__ offs,
                                              const int* __restrict__ csr, const float* __restrict__ dinv,
                                              float* __restrict__ U, int n) {
    int node = blockIdx.x * 4 + (threadIdx.x >> 6);
    int lane = threadIdx.x & 63;
    int half = lane >> 5;
    int l = lane & 31;
    if (node >= n) return;
    const float4* Z4 = (const float4*)Z;
    float4 sum = gather_row_sum(Z4, csr, node, offs[node], offs[node + 1], half, l);
    if (half == 0) {
        float d = dinv[node];
        float4 o;
        o.x = sum.x * d; o.y = sum.y * d; o.z = sum.z * d; o.w = sum.w * d;
        ((float4*)U)[(size_t)node * 32 + l] = o;
    }
}

// ------- layer-3 GEMM fused with pooling via LDS partial: P[g] += relu(U@W3+b3) -------
// sorted batch -> a 128-row block spans ~2-3 graphs; LDS partial [PG][H], ~350 global atomics/block

__global__ __launch_bounds__(256) void gemm_pool_k(const float* __restrict__ in, const float* __restrict__ W,
                                                   const float* __restrict__ bias, const int* __restrict__ batch,
                                                   float* __restrict__ P, int n) {
    __shared__ float WT[8 * CSTRIDE];
    __shared__ float Pp[PG][H + 4];
    stage_WT(W, WT);
    for (int idx = threadIdx.x; idx < PG * H; idx += 256)
        Pp[idx >> 7][idx & 127] = 0.f;
    __syncthreads();
    const int cc = threadIdx.x & 7;
    const int rg = threadIdx.x >> 3;
    const int c0 = cc * 16;
    const int row0 = blockIdx.x * 128 + rg * 4;
    const int rowB = blockIdx.x * 128;
    const float* wt = WT + cc * CSTRIDE;
    const int gmin = batch[rowB < n ? rowB : (n - 1)];

    const float* p[4];
    #pragma unroll
    for (int r = 0; r < 4; ++r) {
        int rr = row0 + r; if (rr > n - 1) rr = n - 1;
        p[r] = in + (size_t)rr * H;
    }

    float acc[4][16];
    #pragma unroll
    for (int r = 0; r < 4; ++r)
        #pragma unroll
        for (int j = 0; j < 16; ++j) acc[r][j] = 0.f;

    for (int k4 = 0; k4 < H / 4; ++k4) {
        float4 a[4];
        #pragma unroll
        for (int r = 0; r < 4; ++r) a[r] = *(const float4*)(p[r] + k4 * 4);
        #pragma unroll
        for (int kk = 0; kk < 4; ++kk) {
            const float* wb = wt + (k4 * 4 + kk) * 16;
            float w[16];
            *(float4*)(w + 0)  = *(const float4*)(wb + 0);
            *(float4*)(w + 4)  = *(const float4*)(wb + 4);
            *(float4*)(w + 8)  = *(const float4*)(wb + 8);
            *(float4*)(w + 12) = *(const float4*)(wb + 12);
            float av[4];
            #pragma unroll
            for (int r = 0; r < 4; ++r) av[r] = ((const float*)&a[r])[kk];
            #pragma unroll
            for (int r = 0; r < 4; ++r)
                #pragma unroll
                for (int j = 0; j < 16; ++j)
                    acc[r][j] = fmaf(av[r], w[j], acc[r][j]);
        }
    }

    // pool epilogue: accumulate into LDS partial keyed by (g - gmin); rare spill -> direct atomics
    #pragma unroll
    for (int r = 0; r < 4; ++r) {
        int row = row0 + r;
        if (row < n) {
            int lg = batch[row] - gmin;
            float h[16];
            #pragma unroll
            for (int j = 0; j < 16; ++j)
                h[j] = fmaxf(acc[r][j] + bias[c0 + j], 0.f);
            if (lg < PG) {
                #pragma unroll
                for (int j = 0; j < 16; ++j) atomicAdd(&Pp[lg][c0 + j], h[j]);
            } else {
                float* pg = P + (size_t)(gmin + lg) * H + c0;
                #pragma unroll
                for (int j = 0; j < 16; ++j) atomicAdd(pg + j, h[j]);
            }
        }
    }
    __syncthreads();
    for (int idx = threadIdx.x; idx < PG * H; idx += 256) {
        int lg = idx >> 7, c = idx & 127;
        float v = Pp[lg][c];
        if (v != 0.f) atomicAdd(&P[(size_t)(gmin + lg) * H + c], v);
    }
}

// ------- fused MLP head: mean + relu(@Wl1+bl1) + relu(@Wl2+bl2) + dot Wl3 + bl3 -------
// P holds SUMS; counts recomputed by binary search on sorted batch

__global__ __launch_bounds__(256) void head_k(const float* __restrict__ P, const int* __restrict__ batch,
                                              const float* __restrict__ Wl1, const float* __restrict__ bl1,
                                              const float* __restrict__ Wl2, const float* __restrict__ bl2,
                                              const float* __restrict__ Wl3, const float* __restrict__ bl3,
                                              float* __restrict__ out, int n, int G) {
    __shared__ float Wb[H * H];
    __shared__ float Tl[H * 133];
    __shared__ float invc[H];
    __shared__ float w3l[H];
    int tid = threadIdx.x;
    int g0 = blockIdx.x * 128;

    if (tid < 128) {
        int g = g0 + tid;
        int lo = 0, hi = n;
        while (lo < hi) { int m = (lo + hi) >> 1; if (batch[m] < g) lo = m + 1; else hi = m; }
        int a0 = lo; hi = n;
        while (lo < hi) { int m = (lo + hi) >> 1; if (batch[m] < g + 1) lo = m + 1; else hi = m; }
        int c = lo - a0;
        invc[tid] = 1.0f / (float)(c > 1 ? c : 1);
        w3l[tid] = Wl3[tid];
    }
    for (int i = tid; i < H * H / 4; i += 256) ((float4*)Wb)[i] = ((const float4*)Wl1)[i];
    __syncthreads();

    const int cc = tid & 7, rg = tid >> 3, c0 = cc * 16;
    float acc[4][16];

    #pragma unroll
    for (int r = 0; r < 4; ++r)
        #pragma unroll
        for (int j = 0; j < 16; ++j) acc[r][j] = 0.f;
    const float4* P4 = (const float4*)P;
    float iv[4];
    #pragma unroll
    for (int r = 0; r < 4; ++r) iv[r] = invc[rg * 4 + r];
    for (int k4 = 0; k4 < H / 4; ++k4) {
        float4 a[4];
        #pragma unroll
        for (int r = 0; r < 4; ++r) {
            float4 v = P4[(size_t)(g0 + rg * 4 + r) * 32 + k4];
            a[r].x = v.x * iv[r]; a[r].y = v.y * iv[r]; a[r].z = v.z * iv[r]; a[r].w = v.w * iv[r];
        }
        const float* wbase = Wb + (k4 * 4) * H + c0;
        #pragma unroll
        for (int kk = 0; kk < 4; ++kk) {
            float w[16];
            *(float4*)(w + 0)  = *(const float4*)(wbase + kk * H + 0);
            *(float4*)(w + 4)  = *(const float4*)(wbase + kk * H + 4);
            *(float4*)(w + 8)  = *(const float4*)(wbase + kk * H + 8);
            *(float4*)(w + 12) = *(const float4*)(wbase + kk * H + 12);
            float av[4];
            #pragma unroll
            for (int r = 0; r < 4; ++r) av[r] = ((const float*)&a[r])[kk];
            #pragma unroll
            for (int r = 0; r < 4; ++r)
                #pragma unroll
                for (int j = 0; j < 16; ++j)
                    acc[r][j] = fmaf(av[r], w[j], acc[r][j]);
        }
    }
    #pragma unroll
    for (int r = 0; r < 4; ++r) {
        int rl = rg * 4 + r;
        #pragma unroll
        for (int j = 0; j < 16; ++j)
            Tl[rl * 133 + c0 + j] = fmaxf(acc[r][j] + bl1[c0 + j], 0.f);
    }
    __syncthreads();
    for (int i = tid; i < H * H / 4; i += 256) ((float4*)Wb)[i] = ((const float4*)Wl2)[i];
    __syncthreads();

    #pragma unroll
    for (int r = 0; r < 4; ++r)
        #pragma unroll
        for (int j = 0; j < 16; ++j) acc[r][j] = 0.f;
    for (int k4 = 0; k4 < H / 4; ++k4) {
        float4 a[4];
        #pragma unroll
        for (int r = 0; r < 4; ++r) a[r] = *(const float4*)(Tl + (rg * 4 + r) * 133 + k4 * 4);
        const float* wbase = Wb + (k4 * 4) * H + c0;
        #pragma unroll
        for (int kk = 0; kk < 4; ++kk) {
            float w[16];
            *(float4*)(w + 0)  = *(const float4*)(wbase + kk * H + 0);
            *(float4*)(w + 4)  = *(const float4*)(wbase + kk * H + 4);
            *(float4*)(w + 8)  = *(const float4*)(wbase + kk * H + 8);
            *(float4*)(w + 12) = *(const float4*)(wbase + kk * H + 12);
            float av[4];
            #pragma unroll
            for (int r = 0; r < 4; ++r) av[r] = ((const float*)&a[r])[kk];
            #pragma unroll
            for (int r = 0; r < 4; ++r)
                #pragma unroll
                for (int j = 0; j < 16; ++j)
                    acc[r][j] = fmaf(av[r], w[j], acc[r][j]);
        }
    }
    float part[4];
    #pragma unroll
    for (int r = 0; r < 4; ++r) {
        float s = 0.f;
        #pragma unroll
        for (int j = 0; j < 16; ++j)
            s += fmaxf(acc[r][j] + bl2[c0 + j], 0.f) * w3l[c0 + j];
        part[r] = s;
    }
    #pragma unroll
    for (int off = 1; off < 8; off <<= 1)
        #pragma unroll
        for (int r = 0; r < 4; ++r) part[r] += __shfl_xor(part[r], off);
    if (cc == 0) {
        float bb = bl3[0];
        #pragma unroll
        for (int r = 0; r < 4; ++r) out[g0 + rg * 4 + r] = part[r] + bb;
    }
}

// ---------------- launch ----------------

extern "C" void kernel_launch(void* const* d_in, const int* in_sizes, int n_in,
                              void* d_out, int out_size, void* d_ws, size_t ws_size,
                              hipStream_t stream) {
    const float* x     = (const float*)d_in[0];
    const int*   ei    = (const int*)d_in[1];
    const int*   batch = (const int*)d_in[2];
    const float* W1  = (const float*)d_in[3];  const float* b1  = (const float*)d_in[4];
    const float* W2  = (const float*)d_in[5];  const float* b2  = (const float*)d_in[6];
    const float* W3  = (const float*)d_in[7];  const float* b3  = (const float*)d_in[8];
    const float* Wl1 = (const float*)d_in[9];  const float* bl1 = (const float*)d_in[10];
    const float* Wl2 = (const float*)d_in[11]; const float* bl2 = (const float*)d_in[12];
    const float* Wl3 = (const float*)d_in[13]; const float* bl3 = (const float*)d_in[14];

    const int N = in_sizes[0];
    const int E = in_sizes[1] / 2;
    const int G = out_size;
    const int* srcp = ei;
    const int* dstp = ei + E;
    const int NB = (N + BN - 1) / BN;    // 196 for N=100000

    char* w = (char*)d_ws;
    size_t off = 0;
    auto alloc = [&](size_t bytes) -> void* {
        void* p = w + off;
        off += (bytes + 255) & ~(size_t)255;
        return p;
    };
    int*    coarse = (int*)alloc((size_t)MAXNB * 4);
    int*    cbase  = (int*)alloc((size_t)(MAXNB + 1) * 4);
    int*    gcur   = (int*)alloc((size_t)MAXNB * 4);
    int*    offs   = (int*)alloc((size_t)(N + 1) * 4);
    int*    csr    = (int*)alloc((size_t)E * 4);
    float*  dinv   = (float*)alloc((size_t)N * 4);
    float*  sbuf   = (float*)alloc((size_t)N * 4);
    float2* td     = (float2*)alloc((size_t)N * 8);
    float*  A      = (float*)alloc((size_t)N * H * 4);   // U2, then U3
    float*  B      = (float*)alloc((size_t)N * H * 4);   // pairbuf, then Z2
    float*  P      = (float*)alloc((size_t)G * H * 4);   // pooled SUMS
    unsigned* pairbuf = (unsigned*)B;   // alias: dead before gemm_post writes Z2
    (void)ws_size; (void)n_in;

    // --- graph build ---
    hipMemsetAsync(coarse, 0, (size_t)MAXNB * 4, stream);
    hipMemsetAsync(P, 0, (size_t)G * H * 4, stream);
    hist_coarse_k<<<256, 256, 0, stream>>>(dstp, coarse, E, NB);
    scan_coarse_k<<<1, 256, 0, stream>>>(coarse, cbase, gcur, offs, NB, N, E);
    scatter_pairs_k<<<(E + CHUNK - 1) / CHUNK, 256, 0, stream>>>(srcp, dstp, gcur, pairbuf, E, NB);
    build_csr_k<<<NB, 512, 0, stream>>>(pairbuf, cbase, x, offs, dinv, sbuf, csr, N);

    // --- layer 1 (scalar feature) ---
    agg1_k<<<(N + 255) / 256, 256, 0, stream>>>(sbuf, offs, csr, dinv, td, N);

    // --- layer 2: scalar-gather fused aggregation, then GEMM ---
    l2_agg_k<<<(N + 3) / 4, 256, 0, stream>>>(td, offs, csr, W1, b1, A, N);
    gemm_post_k<<<(N + 127) / 128, 256, 0, stream>>>(A, W2, b2, dinv, B, N);   // B = Z2

    // --- layer 3: row-gather aggregation, GEMM fused with LDS-partial pooling ---
    agg3_k<<<(N + 3) / 4, 256, 0, stream>>>(B, offs, csr, dinv, A, N);         // A = U3
    gemm_pool_k<<<(N + 127) / 128, 256, 0, stream>>>(A, W3, b3, batch, P, N);  // P = pooled sums

    // --- fused MLP head ---
    head_k<<<(G + 127) / 128, 256, 0, stream>>>(P, batch, Wl1, bl1, Wl2, bl2, Wl3, bl3,
                                                (float*)d_out, N, G);
}

// Round 10
// 505.441 us; speedup vs baseline: 2.1606x; 1.1497x over previous
//
#include <hip/hip_runtime.h>

#define H 128
#define SHIFT 9             // nodes per coarse bucket = 512
#define BN 512
#define MAXNB 256           // max coarse buckets (N <= 131072)
#define CHUNK 4096          // edges per scatter block
#define CAP 16384           // slack capacity per bucket (exp 8192, sigma ~90)
#define CSTRIDE (H * 16 + 4)   // 2052 floats: per-cc transposed W block, conflict-free

// ============ graph build: slack-bucket counting sort (no global histogram pass) ============
// Packing: src < 2^17, local node < 512 -> record = (local<<17)|src fits u32.
// Bucket b owns pairbuf/csr region [b*CAP, (b+1)*CAP); gcur[b] (memset 0) allocates within.

__global__ __launch_bounds__(256) void scatter_pairs_k(const int* __restrict__ src,
                                                       const int* __restrict__ dst,
                                                       int* __restrict__ gcur,
                                                       unsigned* __restrict__ pairbuf,
                                                       int E, int NBv) {
    __shared__ unsigned stage[CHUNK];
    __shared__ unsigned char stb[CHUNK];
    __shared__ int hist[MAXNB], basel[MAXNB], cur[MAXNB], gbase[MAXNB];
    __shared__ int total;
    int tid = threadIdx.x;
    int base = blockIdx.x * CHUNK;

    int mysrc[16], mydst[16];
    #pragma unroll
    for (int i = 0; i < 16; ++i) {
        int e = base + i * 256 + tid;
        if (e < E) { mysrc[i] = src[e]; mydst[i] = dst[e]; } else mydst[i] = -1;
    }
    hist[tid] = 0;
    __syncthreads();
    #pragma unroll
    for (int i = 0; i < 16; ++i)
        if (mydst[i] >= 0) atomicAdd(&hist[mydst[i] >> SHIFT], 1);
    __syncthreads();
    if (tid == 0) {
        int run = 0;
        for (int b = 0; b < NBv; ++b) { basel[b] = run; run += hist[b]; }
        total = run;
    }
    __syncthreads();
    if (tid < NBv) {
        cur[tid] = basel[tid];
        if (hist[tid] > 0) gbase[tid] = tid * CAP + atomicAdd(&gcur[tid], hist[tid]);
    }
    __syncthreads();
    #pragma unroll
    for (int i = 0; i < 16; ++i)
        if (mydst[i] >= 0) {
            int b = mydst[i] >> SHIFT;
            int slot = atomicAdd(&cur[b], 1);
            stage[slot] = ((unsigned)(mydst[i] & (BN - 1)) << 17) | (unsigned)mysrc[i];
            stb[slot] = (unsigned char)b;
        }
    __syncthreads();
    for (int s = tid; s < total; s += 256) {
        int b = stb[s];
        pairbuf[gbase[b] + (s - basel[b])] = stage[s];   // contiguous runs -> full-line writes
    }
}

// one block per bucket: LDS hist + scan -> offs/eend/dinv/s, then in-bucket scatter (L2-local)
__global__ __launch_bounds__(512) void build_csr_k(const unsigned* __restrict__ pairbuf,
                                                   const int* __restrict__ gcur,
                                                   const float* __restrict__ x,
                                                   int* __restrict__ offs, int* __restrict__ eend,
                                                   float* __restrict__ dinv, float* __restrict__ s,
                                                   int* __restrict__ csr, int N) {
    __shared__ int hist[BN];
    __shared__ int cur[BN];
    __shared__ int ps[BN];
    int b = blockIdx.x, tid = threadIdx.x;
    int node0 = b << SHIFT;
    int e0 = b * CAP, e1 = e0 + gcur[b];
    hist[tid] = 0;
    __syncthreads();
    for (int p = e0 + tid; p < e1; p += 512)
        atomicAdd(&hist[pairbuf[p] >> 17], 1);
    __syncthreads();
    int v0 = hist[tid];
    ps[tid] = v0;
    __syncthreads();
    for (int off = 1; off < BN; off <<= 1) {
        int t = (tid >= off) ? ps[tid - off] : 0;
        __syncthreads();
        ps[tid] += t;
        __syncthreads();
    }
    int g0 = e0 + ps[tid] - v0;
    int n0 = node0 + tid;
    if (n0 < N) {
        float d = rsqrtf((float)(v0 + 1));
        offs[n0] = g0;
        eend[n0] = g0 + v0;
        dinv[n0] = d;
        s[n0] = x[n0] * d;      // fused s_k
    }
    cur[tid] = g0;
    __syncthreads();
    for (int p = e0 + tid; p < e1; p += 512) {
        unsigned v = pairbuf[p];
        int pos = atomicAdd(&cur[v >> 17], 1);
        csr[pos] = (int)(v & 0x1FFFFu);
    }
}

// ---------------- layer 1: t_i = dinv_i*(s_i + sum s_src); emits (t, dinv) pairs ----------------

__global__ void agg1_k(const float* __restrict__ s, const int* __restrict__ offs,
                       const int* __restrict__ eend, const int* __restrict__ csr,
                       const float* __restrict__ dinv, float2* __restrict__ td, int n) {
    int i = blockIdx.x * blockDim.x + threadIdx.x;
    if (i >= n) return;
    float sum = s[i];
    int e0 = offs[i], e1 = eend[i];
    float a0 = 0.f, a1 = 0.f, a2 = 0.f, a3 = 0.f;
    int p = e0;
    for (; p + 4 <= e1; p += 4) {
        a0 += s[csr[p]]; a1 += s[csr[p + 1]]; a2 += s[csr[p + 2]]; a3 += s[csr[p + 3]];
    }
    for (; p < e1; ++p) sum += s[csr[p]];
    sum += (a0 + a1) + (a2 + a3);
    float d = dinv[i];
    td[i] = make_float2(sum * d, d);
}

// ------- layer-2 fused aggregation over SCALARS (aggregate-then-GEMM algebra) -------
// U2_i = dinv_i * sum_{j in N(i)+self} dinv_j * relu(t_j*w1 + b1)

__global__ __launch_bounds__(256) void l2_agg_k(const float2* __restrict__ td,
                                                const int* __restrict__ offs,
                                                const int* __restrict__ eend,
                                                const int* __restrict__ csr,
                                                const float* __restrict__ w1,
                                                const float* __restrict__ b1,
                                                float* __restrict__ U, int n) {
    int node = blockIdx.x * 4 + (threadIdx.x >> 6);
    int lane = threadIdx.x & 63;
    if (node >= n) return;
    float wa = w1[lane],      wb = w1[lane + 64];
    float ba = b1[lane],      bb = b1[lane + 64];
    float2 self = td[node];
    float sa = fmaxf(fmaf(self.x, wa, ba), 0.f) * self.y;
    float sb = fmaxf(fmaf(self.x, wb, bb), 0.f) * self.y;
    int e0 = offs[node], e1 = eend[node];
    int p = e0;
    for (; p + 8 <= e1; p += 8) {
        float2 v[8];
        #pragma unroll
        for (int u = 0; u < 8; ++u) v[u] = td[csr[p + u]];
        #pragma unroll
        for (int u = 0; u < 8; ++u) {
            sa = fmaf(fmaxf(fmaf(v[u].x, wa, ba), 0.f), v[u].y, sa);
            sb = fmaf(fmaxf(fmaf(v[u].x, wb, bb), 0.f), v[u].y, sb);
        }
    }
    for (; p < e1; ++p) {
        float2 v = td[csr[p]];
        sa = fmaf(fmaxf(fmaf(v.x, wa, ba), 0.f), v.y, sa);
        sb = fmaf(fmaxf(fmaf(v.x, wb, bb), 0.f), v.y, sb);
    }
    float d = self.y;
    U[(size_t)node * H + lane]      = sa * d;
    U[(size_t)node * H + lane + 64] = sb * d;
}

// ---- conflict-free W staging: WT[cc][k][j], stride CSTRIDE per cc ----

__device__ __forceinline__ void stage_WT(const float* __restrict__ W, float* __restrict__ WT) {
    for (int idx = threadIdx.x; idx < H * H / 4; idx += 256) {
        float4 v = ((const float4*)W)[idx];
        int k  = idx >> 5;
        int c4 = idx & 31;
        int cc = c4 >> 2;
        int j  = (c4 & 3) * 4;
        *(float4*)(WT + cc * CSTRIDE + k * 16 + j) = v;
    }
}

// ------- GEMM with post-activation row scale: Z2 = pscale[row] * relu(in@W + bias) -------

__global__ __launch_bounds__(256) void gemm_post_k(const float* __restrict__ in, const float* __restrict__ W,
                                                   const float* __restrict__ bias, const float* __restrict__ pscale,
                                                   float* __restrict__ out, int n) {
    __shared__ float WT[8 * CSTRIDE];
    stage_WT(W, WT);
    __syncthreads();
    const int cc = threadIdx.x & 7;
    const int rg = threadIdx.x >> 3;
    const int c0 = cc * 16;
    const int row0 = blockIdx.x * 128 + rg * 4;
    const float* wt = WT + cc * CSTRIDE;

    const float* p[4];
    #pragma unroll
    for (int r = 0; r < 4; ++r) {
        int rr = row0 + r; if (rr > n - 1) rr = n - 1;
        p[r] = in + (size_t)rr * H;
    }

    float acc[4][16];
    #pragma unroll
    for (int r = 0; r < 4; ++r)
        #pragma unroll
        for (int j = 0; j < 16; ++j) acc[r][j] = 0.f;

    for (int k4 = 0; k4 < H / 4; ++k4) {
        float4 a[4];
        #pragma unroll
        for (int r = 0; r < 4; ++r) a[r] = *(const float4*)(p[r] + k4 * 4);
        #pragma unroll
        for (int kk = 0; kk < 4; ++kk) {
            const float* wb = wt + (k4 * 4 + kk) * 16;
            float w[16];
            *(float4*)(w + 0)  = *(const float4*)(wb + 0);
            *(float4*)(w + 4)  = *(const float4*)(wb + 4);
            *(float4*)(w + 8)  = *(const float4*)(wb + 8);
            *(float4*)(w + 12) = *(const float4*)(wb + 12);
            float av[4];
            #pragma unroll
            for (int r = 0; r < 4; ++r) av[r] = ((const float*)&a[r])[kk];
            #pragma unroll
            for (int r = 0; r < 4; ++r)
                #pragma unroll
                for (int j = 0; j < 16; ++j)
                    acc[r][j] = fmaf(av[r], w[j], acc[r][j]);
        }
    }

    #pragma unroll
    for (int r = 0; r < 4; ++r) {
        int row = row0 + r;
        if (row < n) {
            float sc = pscale[row];
            float* orow = out + (size_t)row * H + c0;
            #pragma unroll
            for (int j4 = 0; j4 < 4; ++j4) {
                float4 o;
                o.x = fmaxf(acc[r][j4 * 4 + 0] + bias[c0 + j4 * 4 + 0], 0.f) * sc;
                o.y = fmaxf(acc[r][j4 * 4 + 1] + bias[c0 + j4 * 4 + 1], 0.f) * sc;
                o.z = fmaxf(acc[r][j4 * 4 + 2] + bias[c0 + j4 * 4 + 2], 0.f) * sc;
                o.w = fmaxf(acc[r][j4 * 4 + 3] + bias[c0 + j4 * 4 + 3], 0.f) * sc;
                *(float4*)(orow + j4 * 4) = o;
            }
        }
    }
}

// ------- whole-wave gather of one node's neighbor-row sum -------

__device__ __forceinline__ float4 gather_row_sum(const float4* __restrict__ hs4,
                                                 const int* __restrict__ csr,
                                                 int node, int e0, int e1, int half, int l) {
    float4 acc[8];
    #pragma unroll
    for (int u = 0; u < 8; ++u) acc[u] = make_float4(0.f, 0.f, 0.f, 0.f);
    if (half == 0) acc[0] = hs4[(size_t)node * 32 + l];   // self loop
    int q = e0;
    for (; q + 15 < e1; q += 16) {
        int idx[8];
        #pragma unroll
        for (int u = 0; u < 8; ++u) idx[u] = csr[q + 2 * u + half];
        #pragma unroll
        for (int u = 0; u < 8; ++u) {
            float4 v = hs4[(size_t)idx[u] * 32 + l];
            acc[u].x += v.x; acc[u].y += v.y; acc[u].z += v.z; acc[u].w += v.w;
        }
    }
    for (; q + 7 < e1; q += 8) {
        int idx[4];
        #pragma unroll
        for (int u = 0; u < 4; ++u) idx[u] = csr[q + 2 * u + half];
        #pragma unroll
        for (int u = 0; u < 4; ++u) {
            float4 v = hs4[(size_t)idx[u] * 32 + l];
            acc[u].x += v.x; acc[u].y += v.y; acc[u].z += v.z; acc[u].w += v.w;
        }
    }
    for (; q < e1; q += 2) {
        int off = q + half;
        if (off < e1) {
            float4 v = hs4[(size_t)csr[off] * 32 + l];
            acc[0].x += v.x; acc[0].y += v.y; acc[0].z += v.z; acc[0].w += v.w;
        }
    }
    float4 sum;
    sum.x = ((acc[0].x + acc[1].x) + (acc[2].x + acc[3].x)) + ((acc[4].x + acc[5].x) + (acc[6].x + acc[7].x));
    sum.y = ((acc[0].y + acc[1].y) + (acc[2].y + acc[3].y)) + ((acc[4].y + acc[5].y) + (acc[6].y + acc[7].y));
    sum.z = ((acc[0].z + acc[1].z) + (acc[2].z + acc[3].z)) + ((acc[4].z + acc[5].z) + (acc[6].z + acc[7].z));
    sum.w = ((acc[0].w + acc[1].w) + (acc[2].w + acc[3].w)) + ((acc[4].w + acc[5].w) + (acc[6].w + acc[7].w));
    sum.x += __shfl_xor(sum.x, 32);
    sum.y += __shfl_xor(sum.y, 32);
    sum.z += __shfl_xor(sum.z, 32);
    sum.w += __shfl_xor(sum.w, 32);
    return sum;
}

// ------- layer-3 aggregation of Z2 rows: U3_i = dinv_i * (Z2_i + sum Z2_src) -------

__global__ __launch_bounds__(256) void agg3_k(const float* __restrict__ Z, const int* __restrict__ offs,
                                              const int* __restrict__ eend, const int* __restrict__ csr,
                                              const float* __restrict__ dinv,
                                              float* __restrict__ U, int n) {
    int node = blockIdx.x * 4 + (threadIdx.x >> 6);
    int lane = threadIdx.x & 63;
    int half = lane >> 5;
    int l = lane & 31;
    if (node >= n) return;
    const float4* Z4 = (const float4*)Z;
    float4 sum = gather_row_sum(Z4, csr, node, offs[node], eend[node], half, l);
    if (half == 0) {
        float d = dinv[node];
        float4 o;
        o.x = sum.x * d; o.y = sum.y * d; o.z = sum.z * d; o.w = sum.w * d;
        ((float4*)U)[(size_t)node * 32 + l] = o;
    }
}

// ------- layer-3 GEMM: h3 = relu(U3@W3 + b3) -------

__global__ __launch_bounds__(256) void gemm_k(const float* __restrict__ in, const float* __restrict__ W,
                                              const float* __restrict__ bias,
                                              float* __restrict__ out, int n) {
    __shared__ float WT[8 * CSTRIDE];
    stage_WT(W, WT);
    __syncthreads();
    const int cc = threadIdx.x & 7;
    const int rg = threadIdx.x >> 3;
    const int c0 = cc * 16;
    const int row0 = blockIdx.x * 128 + rg * 4;
    const float* wt = WT + cc * CSTRIDE;

    const float* p[4];
    #pragma unroll
    for (int r = 0; r < 4; ++r) {
        int rr = row0 + r; if (rr > n - 1) rr = n - 1;
        p[r] = in + (size_t)rr * H;
    }

    float acc[4][16];
    #pragma unroll
    for (int r = 0; r < 4; ++r)
        #pragma unroll
        for (int j = 0; j < 16; ++j) acc[r][j] = 0.f;

    for (int k4 = 0; k4 < H / 4; ++k4) {
        float4 a[4];
        #pragma unroll
        for (int r = 0; r < 4; ++r) a[r] = *(const float4*)(p[r] + k4 * 4);
        #pragma unroll
        for (int kk = 0; kk < 4; ++kk) {
            const float* wb = wt + (k4 * 4 + kk) * 16;
            float w[16];
            *(float4*)(w + 0)  = *(const float4*)(wb + 0);
            *(float4*)(w + 4)  = *(const float4*)(wb + 4);
            *(float4*)(w + 8)  = *(const float4*)(wb + 8);
            *(float4*)(w + 12) = *(const float4*)(wb + 12);
            float av[4];
            #pragma unroll
            for (int r = 0; r < 4; ++r) av[r] = ((const float*)&a[r])[kk];
            #pragma unroll
            for (int r = 0; r < 4; ++r)
                #pragma unroll
                for (int j = 0; j < 16; ++j)
                    acc[r][j] = fmaf(av[r], w[j], acc[r][j]);
        }
    }

    #pragma unroll
    for (int r = 0; r < 4; ++r) {
        int row = row0 + r;
        if (row < n) {
            float* orow = out + (size_t)row * H + c0;
            #pragma unroll
            for (int j4 = 0; j4 < 4; ++j4) {
                float4 o;
                o.x = fmaxf(acc[r][j4 * 4 + 0] + bias[c0 + j4 * 4 + 0], 0.f);
                o.y = fmaxf(acc[r][j4 * 4 + 1] + bias[c0 + j4 * 4 + 1], 0.f);
                o.z = fmaxf(acc[r][j4 * 4 + 2] + bias[c0 + j4 * 4 + 2], 0.f);
                o.w = fmaxf(acc[r][j4 * 4 + 3] + bias[c0 + j4 * 4 + 3], 0.f);
                *(float4*)(orow + j4 * 4) = o;
            }
        }
    }
}

// ---------------- pooling (binary search over sorted batch ids; overwrite, no atomics) --------

__global__ __launch_bounds__(128) void pool_k(const float* __restrict__ h, const int* __restrict__ batch,
                                              float* __restrict__ P, int n, int G) {
    int g = blockIdx.x, f = threadIdx.x;
    int lo = 0, hi = n;
    while (lo < hi) { int m = (lo + hi) >> 1; if (batch[m] < g) lo = m + 1; else hi = m; }
    int s0 = lo;
    hi = n;
    while (lo < hi) { int m = (lo + hi) >> 1; if (batch[m] < g + 1) lo = m + 1; else hi = m; }
    int s1 = lo;
    float a0 = 0.f, a1 = 0.f, a2 = 0.f, a3 = 0.f;
    int i = s0;
    for (; i + 4 <= s1; i += 4) {
        a0 += h[(size_t)i * H + f];
        a1 += h[(size_t)(i + 1) * H + f];
        a2 += h[(size_t)(i + 2) * H + f];
        a3 += h[(size_t)(i + 3) * H + f];
    }
    for (; i < s1; ++i) a0 += h[(size_t)i * H + f];
    float sum = (a0 + a1) + (a2 + a3);
    float c = (float)(s1 - s0); if (c < 1.f) c = 1.f;
    P[(size_t)g * H + f] = sum / c;
}

// ------- fused MLP head: relu(@Wl1+bl1) + relu(@Wl2+bl2) + dot Wl3 + bl3 -------

__global__ __launch_bounds__(256) void head_k(const float* __restrict__ P,
                                              const float* __restrict__ Wl1, const float* __restrict__ bl1,
                                              const float* __restrict__ Wl2, const float* __restrict__ bl2,
                                              const float* __restrict__ Wl3, const float* __restrict__ bl3,
                                              float* __restrict__ out, int G) {
    __shared__ float Wb[H * H];
    __shared__ float Tl[H * 133];
    __shared__ float w3l[H];
    int tid = threadIdx.x;
    int g0 = blockIdx.x * 128;

    if (tid < 128) w3l[tid] = Wl3[tid];
    for (int i = tid; i < H * H / 4; i += 256) ((float4*)Wb)[i] = ((const float4*)Wl1)[i];
    __syncthreads();

    const int cc = tid & 7, rg = tid >> 3, c0 = cc * 16;
    float acc[4][16];

    #pragma unroll
    for (int r = 0; r < 4; ++r)
        #pragma unroll
        for (int j = 0; j < 16; ++j) acc[r][j] = 0.f;
    const float4* P4 = (const float4*)P;
    for (int k4 = 0; k4 < H / 4; ++k4) {
        float4 a[4];
        #pragma unroll
        for (int r = 0; r < 4; ++r) a[r] = P4[(size_t)(g0 + rg * 4 + r) * 32 + k4];
        const float* wbase = Wb + (k4 * 4) * H + c0;
        #pragma unroll
        for (int kk = 0; kk < 4; ++kk) {
            float w[16];
            *(float4*)(w + 0)  = *(const float4*)(wbase + kk * H + 0);
            *(float4*)(w + 4)  = *(const float4*)(wbase + kk * H + 4);
            *(float4*)(w + 8)  = *(const float4*)(wbase + kk * H + 8);
            *(float4*)(w + 12) = *(const float4*)(wbase + kk * H + 12);
            float av[4];
            #pragma unroll
            for (int r = 0; r < 4; ++r) av[r] = ((const float*)&a[r])[kk];
            #pragma unroll
            for (int r = 0; r < 4; ++r)
                #pragma unroll
                for (int j = 0; j < 16; ++j)
                    acc[r][j] = fmaf(av[r], w[j], acc[r][j]);
        }
    }
    #pragma unroll
    for (int r = 0; r < 4; ++r) {
        int rl = rg * 4 + r;
        #pragma unroll
        for (int j = 0; j < 16; ++j)
            Tl[rl * 133 + c0 + j] = fmaxf(acc[r][j] + bl1[c0 + j], 0.f);
    }
    __syncthreads();
    for (int i = tid; i < H * H / 4; i += 256) ((float4*)Wb)[i] = ((const float4*)Wl2)[i];
    __syncthreads();

    #pragma unroll
    for (int r = 0; r < 4; ++r)
        #pragma unroll
        for (int j = 0; j < 16; ++j) acc[r][j] = 0.f;
    for (int k4 = 0; k4 < H / 4; ++k4) {
        float4 a[4];
        #pragma unroll
        for (int r = 0; r < 4; ++r) a[r] = *(const float4*)(Tl + (rg * 4 + r) * 133 + k4 * 4);
        const float* wbase = Wb + (k4 * 4) * H + c0;
        #pragma unroll
        for (int kk = 0; kk < 4; ++kk) {
            float w[16];
            *(float4*)(w + 0)  = *(const float4*)(wbase + kk * H + 0);
            *(float4*)(w + 4)  = *(const float4*)(wbase + kk * H + 4);
            *(float4*)(w + 8)  = *(const float4*)(wbase + kk * H + 8);
            *(float4*)(w + 12) = *(const float4*)(wbase + kk * H + 12);
            float av[4];
            #pragma unroll
            for (int r = 0; r < 4; ++r) av[r] = ((const float*)&a[r])[kk];
            #pragma unroll
            for (int r = 0; r < 4; ++r)
                #pragma unroll
                for (int j = 0; j < 16; ++j)
                    acc[r][j] = fmaf(av[r], w[j], acc[r][j]);
        }
    }
    float part[4];
    #pragma unroll
    for (int r = 0; r < 4; ++r) {
        float s = 0.f;
        #pragma unroll
        for (int j = 0; j < 16; ++j)
            s += fmaxf(acc[r][j] + bl2[c0 + j], 0.f) * w3l[c0 + j];
        part[r] = s;
    }
    #pragma unroll
    for (int off = 1; off < 8; off <<= 1)
        #pragma unroll
        for (int r = 0; r < 4; ++r) part[r] += __shfl_xor(part[r], off);
    if (cc == 0) {
        float bb = bl3[0];
        #pragma unroll
        for (int r = 0; r < 4; ++r) out[g0 + rg * 4 + r] = part[r] + bb;
    }
}

// ---------------- launch ----------------

extern "C" void kernel_launch(void* const* d_in, const int* in_sizes, int n_in,
                              void* d_out, int out_size, void* d_ws, size_t ws_size,
                              hipStream_t stream) {
    const float* x     = (const float*)d_in[0];
    const int*   ei    = (const int*)d_in[1];
    const int*   batch = (const int*)d_in[2];
    const float* W1  = (const float*)d_in[3];  const float* b1  = (const float*)d_in[4];
    const float* W2  = (const float*)d_in[5];  const float* b2  = (const float*)d_in[6];
    const float* W3  = (const float*)d_in[7];  const float* b3  = (const float*)d_in[8];
    const float* Wl1 = (const float*)d_in[9];  const float* bl1 = (const float*)d_in[10];
    const float* Wl2 = (const float*)d_in[11]; const float* bl2 = (const float*)d_in[12];
    const float* Wl3 = (const float*)d_in[13]; const float* bl3 = (const float*)d_in[14];

    const int N = in_sizes[0];
    const int E = in_sizes[1] / 2;
    const int G = out_size;
    const int* srcp = ei;
    const int* dstp = ei + E;
    const int NB = (N + BN - 1) / BN;    // 196 for N=100000

    char* w = (char*)d_ws;
    size_t off = 0;
    auto alloc = [&](size_t bytes) -> void* {
        void* p = w + off;
        off += (bytes + 255) & ~(size_t)255;
        return p;
    };
    int*    gcur   = (int*)alloc((size_t)MAXNB * 4);
    int*    offs   = (int*)alloc((size_t)N * 4);
    int*    eend   = (int*)alloc((size_t)N * 4);
    int*    csr    = (int*)alloc((size_t)NB * CAP * 4);   // bucket-padded
    float*  dinv   = (float*)alloc((size_t)N * 4);
    float*  sbuf   = (float*)alloc((size_t)N * 4);
    float2* td     = (float2*)alloc((size_t)N * 8);
    float*  A      = (float*)alloc((size_t)N * H * 4);   // U2, then U3
    float*  B      = (float*)alloc((size_t)N * H * 4);   // pairbuf, then Z2, then h3
    float*  P      = (float*)alloc((size_t)G * H * 4);   // pooled means
    unsigned* pairbuf = (unsigned*)B;   // alias (NB*CAP*4 = 12.9 MB << N*H*4)
    (void)ws_size; (void)n_in;

    // --- graph build (slack buckets: no histogram pass) ---
    hipMemsetAsync(gcur, 0, (size_t)MAXNB * 4, stream);
    scatter_pairs_k<<<(E + CHUNK - 1) / CHUNK, 256, 0, stream>>>(srcp, dstp, gcur, pairbuf, E, NB);
    build_csr_k<<<NB, 512, 0, stream>>>(pairbuf, gcur, x, offs, eend, dinv, sbuf, csr, N);

    // --- layer 1 (scalar feature) ---
    agg1_k<<<(N + 255) / 256, 256, 0, stream>>>(sbuf, offs, eend, csr, dinv, td, N);

    // --- layer 2: scalar-gather fused aggregation, then GEMM ---
    l2_agg_k<<<(N + 3) / 4, 256, 0, stream>>>(td, offs, eend, csr, W1, b1, A, N);
    gemm_post_k<<<(N + 127) / 128, 256, 0, stream>>>(A, W2, b2, dinv, B, N);   // B = Z2

    // --- layer 3: row-gather aggregation, GEMM, pool ---
    agg3_k<<<(N + 3) / 4, 256, 0, stream>>>(B, offs, eend, csr, dinv, A, N);   // A = U3
    gemm_k<<<(N + 127) / 128, 256, 0, stream>>>(A, W3, b3, B, N);              // B = h3
    pool_k<<<G, 128, 0, stream>>>(B, batch, P, N, G);

    // --- fused MLP head ---
    head_k<<<(G + 127) / 128, 256, 0, stream>>>(P, Wl1, bl1, Wl2, bl2, Wl3, bl3,
                                                (float*)d_out, G);
}